// Round 11
// baseline (553.449 us; speedup 1.0000x reference)
//
#include <hip/hip_runtime.h>
#include <stdint.h>
#include <stddef.h>

typedef unsigned int u32;
typedef unsigned long long u64;
typedef unsigned short u16;
typedef unsigned char u8;

#define NB 4
#define NLEV 5
#define NCH 72      // A*C = 9*8
#define NREGCH 36   // A*4
#define TOPK 1000
#define NCAND 5000  // NLEV*TOPK
#define NDET 300
#define NBINS 16384       // fallback hist: sigmoid float bits >> 16
#define CAP 8192          // per-(b,level) filtered-candidate buffer
#define FASTCAP 2048      // fast-path key limit (2 keys/thread @ 1024 thr)
#define CHUNK 8192
#define NCHUNK_IMG 50     // 36+9+3+1+1
#define IMGSZ 512.0f
#define SCORE_TH 0.05f
#define NMS_TH 0.5f
#define BBOX_CLIP_F 4.135166556742356f

__constant__ int c_f[NLEV]    = {64, 32, 16, 8, 4};
__constant__ int c_Nloc[NLEV] = {4096, 1024, 256, 64, 16};
__constant__ int c_lg2[NLEV]  = {12, 10, 8, 6, 4};
// logit prefilter thresholds: ~1400 expected survivors at levels 0-3 (10-sigma
// margins vs both TOPK=1000 and FASTCAP=2048); level 4 unfiltered (1152 total).
__constant__ float c_tau[NLEV] = {2.594f, 2.075f, 1.433f, 0.513f, -1e30f};

// ---- XLA-CPU-style sigmoid: logistic(x) = 0.5 + 0.5*tanh(0.5*x), fast-tanh poly, no FMA ----
__device__ __forceinline__ float xla_tanh_f32(float x) {
  float ax = fabsf(x);
  float xc = fminf(fmaxf(x, -7.90531110763549805f), 7.90531110763549805f);
  float x2 = __fmul_rn(xc, xc);
  float p = -2.76076847742355e-16f;
  p = __fadd_rn(__fmul_rn(x2, p), 2.00018790482477e-13f);
  p = __fadd_rn(__fmul_rn(x2, p), -8.60467152213735e-11f);
  p = __fadd_rn(__fmul_rn(x2, p), 5.12229709037114e-08f);
  p = __fadd_rn(__fmul_rn(x2, p), 1.48572235717979e-05f);
  p = __fadd_rn(__fmul_rn(x2, p), 6.37261928875436e-04f);
  p = __fadd_rn(__fmul_rn(x2, p), 4.89352455891786e-03f);
  float num = __fmul_rn(xc, p);
  float q = 1.19825839466702e-06f;
  q = __fadd_rn(__fmul_rn(x2, q), 1.18534705686654e-04f);
  q = __fadd_rn(__fmul_rn(x2, q), 2.26843463243900e-03f);
  q = __fadd_rn(__fmul_rn(x2, q), 4.89352518554385e-03f);
  float r = __fdiv_rn(num, q);
  return (ax < 0.0004f) ? x : r;
}
__device__ __forceinline__ float sigmoid_ref(float x) {
  return __fadd_rn(0.5f, __fmul_rn(0.5f, xla_tanh_f32(__fmul_rn(0.5f, x))));
}

struct ClsPtrs { const float* p[NLEV]; };
struct LevelPtrs { const float* reg[NLEV]; const float* anc[NLEV]; };

__device__ __forceinline__ void chunk_map(int bid, int& b, int& level, int& chunk) {
  b = bid / NCHUNK_IMG;
  int cid = bid % NCHUNK_IMG;
  if      (cid < 36) { level = 0; chunk = cid; }
  else if (cid < 45) { level = 1; chunk = cid - 36; }
  else if (cid < 48) { level = 2; chunk = cid - 45; }
  else if (cid < 49) { level = 3; chunk = cid - 48; }
  else               { level = 4; chunk = cid - 49; }
}

// ---- K1: logit-prefilter; ONE global atomic per block (two-pass ballot scheme) ----
__global__ __launch_bounds__(256)
void k_filter(ClsPtrs cp, u32* __restrict__ selcnt, u64* __restrict__ sel) {
  int b, level, chunk;
  chunk_map(blockIdx.x, b, level, chunk);
  int Nloc = c_Nloc[level], lg2 = c_lg2[level];
  int Nsc = Nloc * NCH;
  int g = b * NLEV + level;
  const float* cls = cp.p[level] + (size_t)b * Nsc;
  float tau = c_tau[level];
  int base = chunk * CHUNK;
  int end = base + CHUNK; if (end > Nsc) end = Nsc;
  int wid = threadIdx.x >> 6, lane = threadIdx.x & 63;
  u64 lowm = (1ull << lane) - 1ull;
  __shared__ u32 wcnt[4];
  __shared__ u32 s_gbase;
  u32 mycnt = 0;
  for (int i = base + threadIdx.x; i < end; i += 256) {
    u64 mk = __ballot((int)(cls[i] > tau));
    mycnt += (u32)__popcll(mk);
  }
  if (lane == 0) wcnt[wid] = mycnt;
  __syncthreads();
  u32 wbase = 0, tot = 0;
  for (int w = 0; w < 4; ++w) { u32 c = wcnt[w]; if (w < wid) wbase += c; tot += c; }
  if (threadIdx.x == 0 && tot) s_gbase = atomicAdd(&selcnt[g], tot);
  __syncthreads();
  if (!tot) return;
  u32 gb = s_gbase;
  u32 run = 0;
  for (int i = base + threadIdx.x; i < end; i += 256) {
    float x = cls[i];
    bool selp = x > tau;                 // monotone sigmoid => logit-space superset filter
    u64 mk = __ballot((int)selp);
    if (selp) {
      u32 pos = gb + wbase + run + (u32)__popcll(mk & lowm);
      if (pos < CAP) {
        u32 bits = __float_as_uint(sigmoid_ref(x));
        int ch = i >> lg2;
        int loc = i & (Nloc - 1);
        u32 e = (u32)(loc * NCH + ch);   // flat score index ((y*f+x)*9+a)*8+c
        sel[(size_t)g * CAP + pos] = ((u64)bits << 32) | (u32)(~e);
      }
    }
    run += (u32)__popcll(mk);
  }
}

// ---- K2: exact top-1000 by rank; guarded fast path + full histogram fallback ----
__global__ __launch_bounds__(1024)
void k_rank(ClsPtrs cp, const u32* __restrict__ selcnt, const u64* __restrict__ sel,
            float* __restrict__ cand_s, u32* __restrict__ cand_t) {
  __shared__ union { u32 hist[NBINS]; u64 keys[CAP]; } sh;  // 64 KB
  __shared__ u32 part[1024];
  __shared__ u32 s_last;
  __shared__ u32 s_cnt;
  __shared__ int s_cut;
  int g = blockIdx.x;
  int b = g / NLEV, l = g % NLEV;
  int Nloc = c_Nloc[l], lg2 = c_lg2[l];
  int Nsc = Nloc * NCH;
  int tid = threadIdx.x;
  int lane = tid & 63;
  u64 lowm = (1ull << lane) - 1ull;
  int obase = b * NCAND + l * TOPK;
  u32 cnt = selcnt[g];
  bool fast = (cnt >= TOPK) && (cnt <= FASTCAP);
  if (fast) {
    u32 m = cnt;
    for (u32 i = tid; i < m; i += 1024) sh.keys[i] = sel[(size_t)g * CAP + i];
    if (tid == 0) s_last = 0;
    __syncthreads();
    u64 k0a = ((u32)tid < m)        ? sh.keys[tid]        : 0ULL;
    u64 k0b = ((u32)tid + 1024 < m) ? sh.keys[tid + 1024] : 0ULL;
    u32 ra = 0, rb = 0;
    #pragma unroll 8
    for (u32 j = 0; j < m; ++j) {
      u64 kj = sh.keys[j];
      ra += (kj > k0a) ? 1u : 0u;
      rb += (kj > k0b) ? 1u : 0u;
    }
    if ((u32)tid < m && ra < TOPK) {
      cand_s[obase + ra] = __uint_as_float((u32)(k0a >> 32));
      u32 e = ~((u32)k0a);
      cand_t[obase + ra] = ((u32)l << 19) | (e & 0x7FFFFu);
      if (ra == TOPK - 1) s_last = (u32)(k0a >> 32);
    }
    if ((u32)tid + 1024 < m && rb < TOPK) {
      cand_s[obase + rb] = __uint_as_float((u32)(k0b >> 32));
      u32 e = ~((u32)k0b);
      cand_t[obase + rb] = ((u32)l << 19) | (e & 0x7FFFFu);
      if (rb == TOPK - 1) s_last = (u32)(k0b >> 32);
    }
    __syncthreads();
    u32 bits_tau = __float_as_uint(sigmoid_ref(c_tau[l]));
    if ((int)cnt != Nsc && !(s_last > bits_tau + 64u)) fast = false;  // block-uniform
  }
  if (fast) return;

  // ---- fallback (never taken for this input; exact for any input) ----
  const float* cls = cp.p[l] + (size_t)b * Nsc;
  for (int i = tid; i < NBINS; i += 1024) sh.hist[i] = 0;
  if (tid == 0) s_cnt = 0;
  __syncthreads();
  for (int i = tid; i < Nsc; i += 1024) {
    float s = sigmoid_ref(cls[i]);
    atomicAdd(&sh.hist[__float_as_uint(s) >> 16], 1u);
  }
  __syncthreads();
  { u32 a = 0; for (int j = 0; j < 16; ++j) a += sh.hist[tid * 16 + j]; part[tid] = a; }
  __syncthreads();
  if (tid == 0) {
    u32 cum = 0; int cut = 0;
    for (int ch = 1023; ch >= 0; --ch) {
      if (cum + part[ch] >= TOPK) {
        u32 cc = cum;
        for (int bin = ch * 16 + 15;; --bin) { cc += sh.hist[bin]; if (cc >= TOPK) { cut = bin; break; } }
        break;
      }
      cum += part[ch];
    }
    s_cut = cut;
  }
  __syncthreads();
  int cut = s_cut;
  __syncthreads();
  for (int i = tid; i < Nsc; i += 1024) {
    float s = sigmoid_ref(cls[i]);
    u32 bits = __float_as_uint(s);
    bool selp = (int)(bits >> 16) >= cut;
    u64 mk = __ballot((int)selp);
    if (selp) {
      int ldr = __builtin_ctzll(mk);
      u32 pos0 = 0;
      if (lane == ldr) pos0 = atomicAdd(&s_cnt, (u32)__popcll(mk));
      pos0 = (u32)__shfl((int)pos0, ldr);
      u32 pos = pos0 + (u32)__popcll(mk & lowm);
      if (pos < CAP) {
        int ch = i >> lg2;
        int loc = i & (Nloc - 1);
        u32 e = (u32)(loc * NCH + ch);
        sh.keys[pos] = ((u64)bits << 32) | (u32)(~e);
      }
    }
  }
  __syncthreads();
  u32 m2 = s_cnt; if (m2 > CAP) m2 = CAP;
  for (u32 i = tid; i < m2; i += 1024) {
    u64 k0 = sh.keys[i];
    u32 r = 0;
    #pragma unroll 8
    for (u32 j = 0; j < m2; ++j) r += (sh.keys[j] > k0) ? 1u : 0u;
    if (r < TOPK) {
      cand_s[obase + r] = __uint_as_float((u32)(k0 >> 32));
      u32 e = ~((u32)k0);
      cand_t[obase + r] = ((u32)l << 19) | (e & 0x7FFFFu);
    }
  }
  for (u32 r = m2 + tid; r < TOPK; r += 1024) {
    cand_s[obase + r] = -1.0f;
    cand_t[obase + r] = ((u32)l << 19) | r;
  }
}

// ---- K3: decode boxes for selected candidates (gathers spread across 80 CUs) ----
__global__ __launch_bounds__(256)
void k_decode(const float* __restrict__ cand_s, const u32* __restrict__ cand_t,
              LevelPtrs lp, float4* __restrict__ cand_box) {
  int b = blockIdx.y;
  int i = blockIdx.x * 256 + threadIdx.x;
  if (i >= NCAND) return;
  float s = cand_s[b * NCAND + i];
  float4 v = make_float4(0.f, 0.f, 0.f, 0.f);
  if (s > SCORE_TH) {
    u32 t = cand_t[b * NCAND + i];
    int lv = (int)(t >> 19);
    u32 e = t & 0x7FFFFu;
    u32 anc = e >> 3;              // loc*9 + a
    int a = (int)(anc % 9u);
    int loc = (int)(anc / 9u);
    int f = c_f[lv];
    int Nloc = f * f;
    const float* rp = lp.reg[lv];
    const float* ap = lp.anc[lv] + (size_t)anc * 4;
    float r0 = rp[((size_t)b * NREGCH + (a * 4 + 0)) * Nloc + loc];
    float r1 = rp[((size_t)b * NREGCH + (a * 4 + 1)) * Nloc + loc];
    float r2 = rp[((size_t)b * NREGCH + (a * 4 + 2)) * Nloc + loc];
    float r3 = rp[((size_t)b * NREGCH + (a * 4 + 3)) * Nloc + loc];
    float a0 = ap[0], a1 = ap[1], a2 = ap[2], a3 = ap[3];
    float aw = __fsub_rn(a2, a0);
    float ah = __fsub_rn(a3, a1);
    float acx = __fadd_rn(a0, __fmul_rn(0.5f, aw));
    float acy = __fadd_rn(a1, __fmul_rn(0.5f, ah));
    float dw = fminf(r2, BBOX_CLIP_F);
    float dh = fminf(r3, BBOX_CLIP_F);
    float pcx = __fadd_rn(__fmul_rn(r0, aw), acx);
    float pcy = __fadd_rn(__fmul_rn(r1, ah), acy);
    float pw = __fmul_rn(expf(dw), aw);
    float ph = __fmul_rn(expf(dh), ah);
    float hx = __fmul_rn(0.5f, pw);
    float hy = __fmul_rn(0.5f, ph);
    v.x = fminf(fmaxf(__fsub_rn(pcx, hx), 0.0f), IMGSZ);
    v.y = fminf(fmaxf(__fsub_rn(pcy, hy), 0.0f), IMGSZ);
    v.z = fminf(fmaxf(__fadd_rn(pcx, hx), 0.0f), IMGSZ);
    v.w = fminf(fmaxf(__fadd_rn(pcy, hy), 0.0f), IMGSZ);
  }
  cand_box[b * NCAND + i] = v;
}

// IoU > thresh predicate — identical _rn sequence as reference; div only when inter>0
__device__ __forceinline__ bool iou_gt4(float4 p, float pa, float4 q, float qa) {
  float ltx = fmaxf(p.x, q.x), lty = fmaxf(p.y, q.y);
  float rx  = fminf(p.z, q.z), ry  = fminf(p.w, q.w);
  float ww = fmaxf(__fsub_rn(rx, ltx), 0.0f);
  float hh = fmaxf(__fsub_rn(ry, lty), 0.0f);
  float inter = __fmul_rn(ww, hh);
  bool res = false;
  if (inter > 0.0f) {
    float denom = fmaxf(__fsub_rn(__fadd_rn(pa, qa), inter), 1e-7f);
    res = __fdiv_rn(inter, denom) > NMS_TH;
  }
  return res;
}
__device__ __forceinline__ float area_rn(float4 p) {
  return __fmul_rn(__fsub_rn(p.z, p.x), __fsub_rn(p.w, p.y));
}

// ---- K4: per-image rank + class-partition, then 8 PARALLEL per-class greedy NMS ----
// Exactness: cross-class suppression impossible (offset boxes in disjoint slabs
// [513c, 513c+512] => IoU==0), and reference computes uncapped greedy keep then
// top-300 of kept => keep set decomposes per class; merge = first 300 kept in
// global rank order.
__global__ __launch_bounds__(1024)
void k_detect(const float* __restrict__ cand_s, const u32* __restrict__ cand_t,
              const float4* __restrict__ cand_box, float* __restrict__ out) {
  __shared__ union {
    u64 keys[NCAND];        // phase 1a/1b
    float4 clsbox[NCAND];   // phase 1e+: class-partitioned OFFSET boxes (80000 B)
  } u;
  __shared__ u16 origIdxByRank[NCAND];  // 10000 B : rank -> original candidate idx
  __shared__ u8  clsByRank[NCAND];      //  5000 B : rank -> class (0xFF invalid)
  __shared__ u16 ord2rank[NCAND];       // 10000 B : class-ordered pos -> rank
  __shared__ u16 kidxc[NCAND];          // 10000 B : per-class kept lists (rel. pos)
  __shared__ u8  keptByRank[NCAND];     //  5000 B
  __shared__ float4 wbox[8][64];        //  8192 B : per-wave group scratch
  __shared__ float  warea[8][64];       //  2048 B
  __shared__ u32 clsCnt[8], clsBase[8];
  __shared__ u32 wsum[16], wpre[16], s_total;
  int b = blockIdx.x, tid = threadIdx.x;
  int wid = tid >> 6, lane = tid & 63;
  u64 lowm = (1ull << lane) - 1ull;

  // ---- 1a: build keys ----
  for (int i = tid; i < NCAND; i += 1024) {
    float s = cand_s[b * NCAND + i];
    u32 t = cand_t[b * NCAND + i];
    u32 hi = (s > SCORE_TH) ? __float_as_uint(s) : 0u;  // invalid -> sorts last
    u.keys[i] = ((u64)hi << 32) | (u32)(~t);
  }
  __syncthreads();
  // ---- 1b: global rank via binary searches; scatter rank-indexed maps ----
  for (int i = tid; i < NCAND; i += 1024) {
    u64 k0 = u.keys[i];
    int l = i / TOPK;
    int rank = i - l * TOPK;
    for (int L = 0; L < NLEV; ++L) {
      if (L == l) continue;
      const u64* A = u.keys + L * TOPK;      // desc-sorted, unique
      int lo = 0, hi2 = TOPK;                // count of A[j] > k0
      while (lo < hi2) { int mid = (lo + hi2) >> 1; if (A[mid] > k0) lo = mid + 1; else hi2 = mid; }
      rank += lo;
    }
    u32 hi = (u32)(k0 >> 32);
    u32 t = ~((u32)k0);
    origIdxByRank[rank] = (u16)i;
    clsByRank[rank] = hi ? (u8)(t & 7u) : (u8)0xFF;
    keptByRank[rank] = 0;
  }
  __syncthreads();
  // ---- 1c: per-class counts (wave c counts class c, stable rank order) ----
  if (wid < 8) {
    u32 cntc = 0;
    for (int g = 0; g < (NCAND + 63) / 64; ++g) {
      int r = g * 64 + lane;
      bool is = (r < NCAND) && (clsByRank[r] == (u8)wid);
      u64 mk = __ballot((int)is);
      cntc += (u32)__popcll(mk);
    }
    if (lane == 0) clsCnt[wid] = cntc;
  }
  __syncthreads();
  if (tid == 0) { u32 a = 0; for (int c = 0; c < 8; ++c) { clsBase[c] = a; a += clsCnt[c]; } }
  __syncthreads();
  // ---- 1e: stable class partition; store OFFSET boxes (keys now dead) ----
  if (wid < 8) {
    u32 basec = clsBase[wid], run = 0;
    float off = __fmul_rn((float)wid, IMGSZ + 1.0f);
    for (int g = 0; g < (NCAND + 63) / 64; ++g) {
      int r = g * 64 + lane;
      bool is = (r < NCAND) && (clsByRank[r] == (u8)wid);
      u64 mk = __ballot((int)is);
      if (is) {
        u32 p = basec + run + (u32)__popcll(mk & lowm);
        int io = origIdxByRank[r];
        float4 v = cand_box[b * NCAND + io];
        float4 q;
        q.x = __fadd_rn(v.x, off); q.y = __fadd_rn(v.y, off);
        q.z = __fadd_rn(v.z, off); q.w = __fadd_rn(v.w, off);
        u.clsbox[p] = q;
        ord2rank[p] = (u16)r;
      }
      run += (u32)__popcll(mk);
    }
  }
  __syncthreads();

  // ---- phase 2: 8 parallel per-class greedy NMS (no barriers, no cap) ----
  if (wid < 8) {
    int cnt = (int)clsCnt[wid], basec = (int)clsBase[wid];
    int nk = 0;
    for (int p0 = 0; p0 < cnt; p0 += 64) {
      int p = p0 + lane;
      bool in = p < cnt;
      float4 q = in ? u.clsbox[basec + p] : make_float4(0.f, 0.f, 0.f, 0.f);
      float areaq = area_rn(q);
      wbox[wid][lane] = q; warea[wid][lane] = areaq;   // same-wave LDS, no barrier
      // phase A: vs my class's kept list (4-wide batched)
      bool sup = false;
      if (in) {
        int k = 0;
        for (; k + 4 <= nk; k += 4) {
          int i0 = kidxc[basec + k + 0], i1 = kidxc[basec + k + 1];
          int i2 = kidxc[basec + k + 2], i3 = kidxc[basec + k + 3];
          float4 b0 = u.clsbox[basec + i0], b1 = u.clsbox[basec + i1];
          float4 b2 = u.clsbox[basec + i2], b3 = u.clsbox[basec + i3];
          sup = sup | iou_gt4(b0, area_rn(b0), q, areaq) | iou_gt4(b1, area_rn(b1), q, areaq)
                    | iou_gt4(b2, area_rn(b2), q, areaq) | iou_gt4(b3, area_rn(b3), q, areaq);
        }
        for (; k < nk; ++k) {
          float4 bk = u.clsbox[basec + kidxc[basec + k]];
          sup = sup | iou_gt4(bk, area_rn(bk), q, areaq);
        }
      }
      u64 pending = __ballot((int)(in && !sup));
      // phase B: intra-group rows (j > lane), whole group is same class
      u64 row = 0;
      if ((pending >> lane) & 1ull) {
        u64 mine = pending & ~((2ull << lane) - 1ull);
        while (mine) {
          int j = __builtin_ctzll(mine); mine &= mine - 1ull;
          if (iou_gt4(q, areaq, wbox[wid][j], warea[wid][j])) row |= (1ull << j);
        }
      }
      u64 nz = __ballot((int)(row != 0ull));
      // phase C: serial greedy within wave; row fetched via shfl from owner lane
      u64 rem = pending;
      while (rem) {
        int r = __builtin_ctzll(rem); rem &= rem - 1ull;
        if (lane == r) {
          kidxc[basec + nk] = (u16)(p0 + r);
          keptByRank[ord2rank[basec + p0 + r]] = 1;
        }
        ++nk;
        if ((nz >> r) & 1ull) {
          u64 rrow = (u64)__shfl((long long)row, r);
          rem &= ~rrow;
        }
      }
    }
  }
  __syncthreads();

  // ---- phase 3: prefix-scan kept marks; emit first 300 in global rank order ----
  int rbase = tid * 5;                      // 1024*5 = 5120 covers 5000
  u32 v = 0;
  for (int j = 0; j < 5; ++j) { int r = rbase + j; if (r < NCAND && keptByRank[r]) v++; }
  u32 x = v;
  for (int d = 1; d < 64; d <<= 1) { u32 y = __shfl_up(x, d); if (lane >= d) x += y; }
  if (lane == 63) wsum[wid] = x;
  __syncthreads();
  if (tid == 0) { u32 a = 0; for (int w = 0; w < 16; ++w) { wpre[w] = a; a += wsum[w]; } s_total = a; }
  __syncthreads();
  u32 pos = wpre[wid] + x - v;              // exclusive prefix of my 5-rank window
  for (int j = 0; j < 5; ++j) {
    int r = rbase + j;
    if (r < NCAND && keptByRank[r]) {
      if (pos < NDET) {
        int io = origIdxByRank[r];
        float4 bx = cand_box[b * NCAND + io];
        float sc = cand_s[b * NCAND + io];
        float lb = (float)clsByRank[r];
        int idx = b * NDET + (int)pos;
        out[(size_t)idx * 4 + 0] = bx.x;
        out[(size_t)idx * 4 + 1] = bx.y;
        out[(size_t)idx * 4 + 2] = bx.z;
        out[(size_t)idx * 4 + 3] = bx.w;
        out[NB * NDET * 4 + idx] = sc;
        out[NB * NDET * 5 + idx] = lb;
      }
      pos++;
    }
  }
  u32 total = s_total < (u32)NDET ? s_total : (u32)NDET;
  for (int k2 = tid; k2 < NDET; k2 += 1024) {
    if ((u32)k2 >= total) {
      int idx = b * NDET + k2;
      out[(size_t)idx * 4 + 0] = 0.f;
      out[(size_t)idx * 4 + 1] = 0.f;
      out[(size_t)idx * 4 + 2] = 0.f;
      out[(size_t)idx * 4 + 3] = 0.f;
      out[NB * NDET * 4 + idx] = 0.f;
      out[NB * NDET * 5 + idx] = -1.0f;
    }
  }
}

extern "C" void kernel_launch(void* const* d_in, const int* in_sizes, int n_in,
                              void* d_out, int out_size, void* d_ws, size_t ws_size,
                              hipStream_t stream) {
  const float* cls[NLEV]; const float* reg[NLEV]; const float* anc[NLEV];
  bool dict_order = (n_in >= 2) && (in_sizes[1] == 4 * NREGCH * 64 * 64);
  for (int l = 0; l < NLEV; ++l) {
    if (dict_order) {
      cls[l] = (const float*)d_in[3 * l + 0];
      reg[l] = (const float*)d_in[3 * l + 1];
      anc[l] = (const float*)d_in[3 * l + 2];
    } else {
      cls[l] = (const float*)d_in[l];
      reg[l] = (const float*)d_in[NLEV + l];
      anc[l] = (const float*)d_in[2 * NLEV + l];
    }
  }

  char* ws = (char*)d_ws;
  size_t off = 0;
  auto alloc = [&](size_t bytes) -> void* {
    void* p = ws + off;
    off = (off + bytes + 255) & ~(size_t)255;
    return p;
  };
  u32*    selcnt   = (u32*)   alloc(20 * 4);
  u64*    sel      = (u64*)   alloc(20ULL * CAP * 8);
  float*  cand_s   = (float*) alloc((size_t)NB * NCAND * 4);
  u32*    cand_t   = (u32*)   alloc((size_t)NB * NCAND * 4);
  float4* cand_box = (float4*)alloc((size_t)NB * NCAND * 16);
  (void)ws_size; (void)out_size;

  hipMemsetAsync(selcnt, 0, 20 * 4, stream);

  ClsPtrs cp;
  for (int l = 0; l < NLEV; ++l) cp.p[l] = cls[l];
  LevelPtrs lp;
  for (int l = 0; l < NLEV; ++l) { lp.reg[l] = reg[l]; lp.anc[l] = anc[l]; }

  k_filter<<<NB * NCHUNK_IMG, 256, 0, stream>>>(cp, selcnt, sel);
  k_rank<<<NB * NLEV, 1024, 0, stream>>>(cp, selcnt, sel, cand_s, cand_t);
  k_decode<<<dim3((NCAND + 255) / 256, NB), 256, 0, stream>>>(cand_s, cand_t, lp, cand_box);
  k_detect<<<NB, 1024, 0, stream>>>(cand_s, cand_t, cand_box, (float*)d_out);
}

// Round 12
// 175.031 us; speedup vs baseline: 3.1620x; 3.1620x over previous
//
#include <hip/hip_runtime.h>
#include <stdint.h>
#include <stddef.h>

typedef unsigned int u32;
typedef unsigned long long u64;
typedef unsigned short u16;
typedef unsigned char u8;

#define NB 4
#define NLEV 5
#define NCH 72      // A*C = 9*8
#define NREGCH 36   // A*4
#define TOPK 1000
#define NCAND 5000  // NLEV*TOPK
#define NDET 300
#define NBINS 16384       // fallback hist: sigmoid float bits >> 16
#define CAP 8192          // per-(b,level) filtered-candidate buffer
#define FASTCAP 2048      // fast-path key limit (2 keys/thread @ 1024 thr)
#define CHUNK 8192
#define NCHUNK_IMG 50     // 36+9+3+1+1
#define IMGSZ 512.0f
#define SCORE_TH 0.05f
#define NMS_TH 0.5f
#define BBOX_CLIP_F 4.135166556742356f

__constant__ int c_f[NLEV]    = {64, 32, 16, 8, 4};
__constant__ int c_Nloc[NLEV] = {4096, 1024, 256, 64, 16};
__constant__ int c_lg2[NLEV]  = {12, 10, 8, 6, 4};
// logit prefilter thresholds: ~1400 expected survivors at levels 0-3 (10-sigma
// margins vs both TOPK=1000 and FASTCAP=2048); level 4 unfiltered (1152 total).
__constant__ float c_tau[NLEV] = {2.594f, 2.075f, 1.433f, 0.513f, -1e30f};

// ---- XLA-CPU-style sigmoid: logistic(x) = 0.5 + 0.5*tanh(0.5*x), fast-tanh poly, no FMA ----
__device__ __forceinline__ float xla_tanh_f32(float x) {
  float ax = fabsf(x);
  float xc = fminf(fmaxf(x, -7.90531110763549805f), 7.90531110763549805f);
  float x2 = __fmul_rn(xc, xc);
  float p = -2.76076847742355e-16f;
  p = __fadd_rn(__fmul_rn(x2, p), 2.00018790482477e-13f);
  p = __fadd_rn(__fmul_rn(x2, p), -8.60467152213735e-11f);
  p = __fadd_rn(__fmul_rn(x2, p), 5.12229709037114e-08f);
  p = __fadd_rn(__fmul_rn(x2, p), 1.48572235717979e-05f);
  p = __fadd_rn(__fmul_rn(x2, p), 6.37261928875436e-04f);
  p = __fadd_rn(__fmul_rn(x2, p), 4.89352455891786e-03f);
  float num = __fmul_rn(xc, p);
  float q = 1.19825839466702e-06f;
  q = __fadd_rn(__fmul_rn(x2, q), 1.18534705686654e-04f);
  q = __fadd_rn(__fmul_rn(x2, q), 2.26843463243900e-03f);
  q = __fadd_rn(__fmul_rn(x2, q), 4.89352518554385e-03f);
  float r = __fdiv_rn(num, q);
  return (ax < 0.0004f) ? x : r;
}
__device__ __forceinline__ float sigmoid_ref(float x) {
  return __fadd_rn(0.5f, __fmul_rn(0.5f, xla_tanh_f32(__fmul_rn(0.5f, x))));
}

struct ClsPtrs { const float* p[NLEV]; };
struct LevelPtrs { const float* reg[NLEV]; const float* anc[NLEV]; };

__device__ __forceinline__ void chunk_map(int bid, int& b, int& level, int& chunk) {
  b = bid / NCHUNK_IMG;
  int cid = bid % NCHUNK_IMG;
  if      (cid < 36) { level = 0; chunk = cid; }
  else if (cid < 45) { level = 1; chunk = cid - 36; }
  else if (cid < 48) { level = 2; chunk = cid - 45; }
  else if (cid < 49) { level = 3; chunk = cid - 48; }
  else               { level = 4; chunk = cid - 49; }
}

// ---- K1: logit-prefilter; ONE global atomic per block (two-pass ballot scheme) ----
__global__ __launch_bounds__(256)
void k_filter(ClsPtrs cp, u32* __restrict__ selcnt, u64* __restrict__ sel) {
  int b, level, chunk;
  chunk_map(blockIdx.x, b, level, chunk);
  int Nloc = c_Nloc[level], lg2 = c_lg2[level];
  int Nsc = Nloc * NCH;
  int g = b * NLEV + level;
  const float* cls = cp.p[level] + (size_t)b * Nsc;
  float tau = c_tau[level];
  int base = chunk * CHUNK;
  int end = base + CHUNK; if (end > Nsc) end = Nsc;
  int wid = threadIdx.x >> 6, lane = threadIdx.x & 63;
  u64 lowm = (1ull << lane) - 1ull;
  __shared__ u32 wcnt[4];
  __shared__ u32 s_gbase;
  u32 mycnt = 0;
  for (int i = base + threadIdx.x; i < end; i += 256) {
    u64 mk = __ballot((int)(cls[i] > tau));
    mycnt += (u32)__popcll(mk);
  }
  if (lane == 0) wcnt[wid] = mycnt;
  __syncthreads();
  u32 wbase = 0, tot = 0;
  for (int w = 0; w < 4; ++w) { u32 c = wcnt[w]; if (w < wid) wbase += c; tot += c; }
  if (threadIdx.x == 0 && tot) s_gbase = atomicAdd(&selcnt[g], tot);
  __syncthreads();
  if (!tot) return;
  u32 gb = s_gbase;
  u32 run = 0;
  for (int i = base + threadIdx.x; i < end; i += 256) {
    float x = cls[i];
    bool selp = x > tau;                 // monotone sigmoid => logit-space superset filter
    u64 mk = __ballot((int)selp);
    if (selp) {
      u32 pos = gb + wbase + run + (u32)__popcll(mk & lowm);
      if (pos < CAP) {
        u32 bits = __float_as_uint(sigmoid_ref(x));
        int ch = i >> lg2;
        int loc = i & (Nloc - 1);
        u32 e = (u32)(loc * NCH + ch);   // flat score index ((y*f+x)*9+a)*8+c
        sel[(size_t)g * CAP + pos] = ((u64)bits << 32) | (u32)(~e);
      }
    }
    run += (u32)__popcll(mk);
  }
}

// ---- K2: exact top-1000 by rank; guarded fast path + full histogram fallback ----
__global__ __launch_bounds__(1024)
void k_rank(ClsPtrs cp, const u32* __restrict__ selcnt, const u64* __restrict__ sel,
            float* __restrict__ cand_s, u32* __restrict__ cand_t) {
  __shared__ union { u32 hist[NBINS]; u64 keys[CAP]; } sh;  // 64 KB
  __shared__ u32 part[1024];
  __shared__ u32 s_last;
  __shared__ u32 s_cnt;
  __shared__ int s_cut;
  int g = blockIdx.x;
  int b = g / NLEV, l = g % NLEV;
  int Nloc = c_Nloc[l], lg2 = c_lg2[l];
  int Nsc = Nloc * NCH;
  int tid = threadIdx.x;
  int lane = tid & 63;
  u64 lowm = (1ull << lane) - 1ull;
  int obase = b * NCAND + l * TOPK;
  u32 cnt = selcnt[g];
  bool fast = (cnt >= TOPK) && (cnt <= FASTCAP);
  if (fast) {
    u32 m = cnt;
    for (u32 i = tid; i < m; i += 1024) sh.keys[i] = sel[(size_t)g * CAP + i];
    if (tid == 0) s_last = 0;
    __syncthreads();
    u64 k0a = ((u32)tid < m)        ? sh.keys[tid]        : 0ULL;
    u64 k0b = ((u32)tid + 1024 < m) ? sh.keys[tid + 1024] : 0ULL;
    u32 ra = 0, rb = 0;
    #pragma unroll 8
    for (u32 j = 0; j < m; ++j) {
      u64 kj = sh.keys[j];
      ra += (kj > k0a) ? 1u : 0u;
      rb += (kj > k0b) ? 1u : 0u;
    }
    if ((u32)tid < m && ra < TOPK) {
      cand_s[obase + ra] = __uint_as_float((u32)(k0a >> 32));
      u32 e = ~((u32)k0a);
      cand_t[obase + ra] = ((u32)l << 19) | (e & 0x7FFFFu);
      if (ra == TOPK - 1) s_last = (u32)(k0a >> 32);
    }
    if ((u32)tid + 1024 < m && rb < TOPK) {
      cand_s[obase + rb] = __uint_as_float((u32)(k0b >> 32));
      u32 e = ~((u32)k0b);
      cand_t[obase + rb] = ((u32)l << 19) | (e & 0x7FFFFu);
      if (rb == TOPK - 1) s_last = (u32)(k0b >> 32);
    }
    __syncthreads();
    u32 bits_tau = __float_as_uint(sigmoid_ref(c_tau[l]));
    if ((int)cnt != Nsc && !(s_last > bits_tau + 64u)) fast = false;  // block-uniform
  }
  if (fast) return;

  // ---- fallback (never taken for this input; exact for any input) ----
  const float* cls = cp.p[l] + (size_t)b * Nsc;
  for (int i = tid; i < NBINS; i += 1024) sh.hist[i] = 0;
  if (tid == 0) s_cnt = 0;
  __syncthreads();
  for (int i = tid; i < Nsc; i += 1024) {
    float s = sigmoid_ref(cls[i]);
    atomicAdd(&sh.hist[__float_as_uint(s) >> 16], 1u);
  }
  __syncthreads();
  { u32 a = 0; for (int j = 0; j < 16; ++j) a += sh.hist[tid * 16 + j]; part[tid] = a; }
  __syncthreads();
  if (tid == 0) {
    u32 cum = 0; int cut = 0;
    for (int ch = 1023; ch >= 0; --ch) {
      if (cum + part[ch] >= TOPK) {
        u32 cc = cum;
        for (int bin = ch * 16 + 15;; --bin) { cc += sh.hist[bin]; if (cc >= TOPK) { cut = bin; break; } }
        break;
      }
      cum += part[ch];
    }
    s_cut = cut;
  }
  __syncthreads();
  int cut = s_cut;
  __syncthreads();
  for (int i = tid; i < Nsc; i += 1024) {
    float s = sigmoid_ref(cls[i]);
    u32 bits = __float_as_uint(s);
    bool selp = (int)(bits >> 16) >= cut;
    u64 mk = __ballot((int)selp);
    if (selp) {
      int ldr = __builtin_ctzll(mk);
      u32 pos0 = 0;
      if (lane == ldr) pos0 = atomicAdd(&s_cnt, (u32)__popcll(mk));
      pos0 = (u32)__shfl((int)pos0, ldr);
      u32 pos = pos0 + (u32)__popcll(mk & lowm);
      if (pos < CAP) {
        int ch = i >> lg2;
        int loc = i & (Nloc - 1);
        u32 e = (u32)(loc * NCH + ch);
        sh.keys[pos] = ((u64)bits << 32) | (u32)(~e);
      }
    }
  }
  __syncthreads();
  u32 m2 = s_cnt; if (m2 > CAP) m2 = CAP;
  for (u32 i = tid; i < m2; i += 1024) {
    u64 k0 = sh.keys[i];
    u32 r = 0;
    #pragma unroll 8
    for (u32 j = 0; j < m2; ++j) r += (sh.keys[j] > k0) ? 1u : 0u;
    if (r < TOPK) {
      cand_s[obase + r] = __uint_as_float((u32)(k0 >> 32));
      u32 e = ~((u32)k0);
      cand_t[obase + r] = ((u32)l << 19) | (e & 0x7FFFFu);
    }
  }
  for (u32 r = m2 + tid; r < TOPK; r += 1024) {
    cand_s[obase + r] = -1.0f;
    cand_t[obase + r] = ((u32)l << 19) | r;
  }
}

// ---- K3: decode boxes for selected candidates (gathers spread across 80 CUs) ----
__global__ __launch_bounds__(256)
void k_decode(const float* __restrict__ cand_s, const u32* __restrict__ cand_t,
              LevelPtrs lp, float4* __restrict__ cand_box) {
  int b = blockIdx.y;
  int i = blockIdx.x * 256 + threadIdx.x;
  if (i >= NCAND) return;
  float s = cand_s[b * NCAND + i];
  float4 v = make_float4(0.f, 0.f, 0.f, 0.f);
  if (s > SCORE_TH) {
    u32 t = cand_t[b * NCAND + i];
    int lv = (int)(t >> 19);
    u32 e = t & 0x7FFFFu;
    u32 anc = e >> 3;              // loc*9 + a
    int a = (int)(anc % 9u);
    int loc = (int)(anc / 9u);
    int f = c_f[lv];
    int Nloc = f * f;
    const float* rp = lp.reg[lv];
    const float* ap = lp.anc[lv] + (size_t)anc * 4;
    float r0 = rp[((size_t)b * NREGCH + (a * 4 + 0)) * Nloc + loc];
    float r1 = rp[((size_t)b * NREGCH + (a * 4 + 1)) * Nloc + loc];
    float r2 = rp[((size_t)b * NREGCH + (a * 4 + 2)) * Nloc + loc];
    float r3 = rp[((size_t)b * NREGCH + (a * 4 + 3)) * Nloc + loc];
    float a0 = ap[0], a1 = ap[1], a2 = ap[2], a3 = ap[3];
    float aw = __fsub_rn(a2, a0);
    float ah = __fsub_rn(a3, a1);
    float acx = __fadd_rn(a0, __fmul_rn(0.5f, aw));
    float acy = __fadd_rn(a1, __fmul_rn(0.5f, ah));
    float dw = fminf(r2, BBOX_CLIP_F);
    float dh = fminf(r3, BBOX_CLIP_F);
    float pcx = __fadd_rn(__fmul_rn(r0, aw), acx);
    float pcy = __fadd_rn(__fmul_rn(r1, ah), acy);
    float pw = __fmul_rn(expf(dw), aw);
    float ph = __fmul_rn(expf(dh), ah);
    float hx = __fmul_rn(0.5f, pw);
    float hy = __fmul_rn(0.5f, ph);
    v.x = fminf(fmaxf(__fsub_rn(pcx, hx), 0.0f), IMGSZ);
    v.y = fminf(fmaxf(__fsub_rn(pcy, hy), 0.0f), IMGSZ);
    v.z = fminf(fmaxf(__fadd_rn(pcx, hx), 0.0f), IMGSZ);
    v.w = fminf(fmaxf(__fadd_rn(pcy, hy), 0.0f), IMGSZ);
  }
  cand_box[b * NCAND + i] = v;
}

// IoU > thresh predicate — identical _rn sequence as reference; div only when inter>0
__device__ __forceinline__ bool iou_gt4(float4 p, float pa, float4 q, float qa) {
  float ltx = fmaxf(p.x, q.x), lty = fmaxf(p.y, q.y);
  float rx  = fminf(p.z, q.z), ry  = fminf(p.w, q.w);
  float ww = fmaxf(__fsub_rn(rx, ltx), 0.0f);
  float hh = fmaxf(__fsub_rn(ry, lty), 0.0f);
  float inter = __fmul_rn(ww, hh);
  bool res = false;
  if (inter > 0.0f) {
    float denom = fmaxf(__fsub_rn(__fadd_rn(pa, qa), inter), 1e-7f);
    res = __fdiv_rn(inter, denom) > NMS_TH;
  }
  return res;
}
__device__ __forceinline__ float area_rn(float4 p) {
  return __fmul_rn(__fsub_rn(p.z, p.x), __fsub_rn(p.w, p.y));
}

// ---- K4: per-image rank + class-partition, then 8 parallel per-class greedy NMS
//      processed in rank-prefix ROUNDS with block-wide early exit at 300 kept ----
// Exactness: cross-class suppression impossible (offset boxes in disjoint slabs);
// greedy keep decisions only look backward at kept boxes, so marks for rank<rlim
// are final after the round; if >=300 kept in prefix, global first-300 lie inside.
__global__ __launch_bounds__(1024)
void k_detect(const float* __restrict__ cand_s, const u32* __restrict__ cand_t,
              const float4* __restrict__ cand_box, float* __restrict__ out) {
  __shared__ union {
    u64 keys[NCAND];        // phase 1a/1b
    float4 clsbox[NCAND];   // phase 1e+: class-partitioned OFFSET boxes (80000 B)
  } u;
  __shared__ u16 origIdxByRank[NCAND];  // rank -> original candidate idx
  __shared__ u8  clsByRank[NCAND];      // rank -> class (0xFF invalid)
  __shared__ u16 ord2rank[NCAND];       // class-ordered pos -> rank (increasing/class)
  __shared__ u16 kidxc[NCAND];          // per-class kept lists (class-relative pos)
  __shared__ u8  keptByRank[NCAND];
  __shared__ float4 wbox[8][64];
  __shared__ float  warea[8][64];
  __shared__ u32 clsCnt[8], clsBase[8];
  __shared__ u32 wsum[16], wpre[16], s_total;
  int b = blockIdx.x, tid = threadIdx.x;
  int wid = tid >> 6, lane = tid & 63;
  u64 lowm = (1ull << lane) - 1ull;

  // ---- 1a: build keys ----
  for (int i = tid; i < NCAND; i += 1024) {
    float s = cand_s[b * NCAND + i];
    u32 t = cand_t[b * NCAND + i];
    u32 hi = (s > SCORE_TH) ? __float_as_uint(s) : 0u;  // invalid -> sorts last
    u.keys[i] = ((u64)hi << 32) | (u32)(~t);
  }
  __syncthreads();
  // ---- 1b: global rank via binary searches; scatter rank-indexed maps ----
  for (int i = tid; i < NCAND; i += 1024) {
    u64 k0 = u.keys[i];
    int l = i / TOPK;
    int rank = i - l * TOPK;
    for (int L = 0; L < NLEV; ++L) {
      if (L == l) continue;
      const u64* A = u.keys + L * TOPK;      // desc-sorted, unique
      int lo = 0, hi2 = TOPK;                // count of A[j] > k0
      while (lo < hi2) { int mid = (lo + hi2) >> 1; if (A[mid] > k0) lo = mid + 1; else hi2 = mid; }
      rank += lo;
    }
    u32 hi = (u32)(k0 >> 32);
    u32 t = ~((u32)k0);
    origIdxByRank[rank] = (u16)i;
    clsByRank[rank] = hi ? (u8)(t & 7u) : (u8)0xFF;
    keptByRank[rank] = 0;
  }
  __syncthreads();
  // ---- 1c: per-class counts (wave c counts class c, stable rank order) ----
  if (wid < 8) {
    u32 cntc = 0;
    for (int g = 0; g < (NCAND + 63) / 64; ++g) {
      int r = g * 64 + lane;
      bool is = (r < NCAND) && (clsByRank[r] == (u8)wid);
      u64 mk = __ballot((int)is);
      cntc += (u32)__popcll(mk);
    }
    if (lane == 0) clsCnt[wid] = cntc;
  }
  __syncthreads();
  if (tid == 0) { u32 a = 0; for (int c = 0; c < 8; ++c) { clsBase[c] = a; a += clsCnt[c]; } }
  __syncthreads();
  // ---- 1e: stable class partition; store OFFSET boxes (keys now dead) ----
  if (wid < 8) {
    u32 basec = clsBase[wid], run = 0;
    float off = __fmul_rn((float)wid, IMGSZ + 1.0f);
    for (int g = 0; g < (NCAND + 63) / 64; ++g) {
      int r = g * 64 + lane;
      bool is = (r < NCAND) && (clsByRank[r] == (u8)wid);
      u64 mk = __ballot((int)is);
      if (is) {
        u32 p = basec + run + (u32)__popcll(mk & lowm);
        int io = origIdxByRank[r];
        float4 v = cand_box[b * NCAND + io];
        float4 q;
        q.x = __fadd_rn(v.x, off); q.y = __fadd_rn(v.y, off);
        q.z = __fadd_rn(v.z, off); q.w = __fadd_rn(v.w, off);
        u.clsbox[p] = q;
        ord2rank[p] = (u16)r;
      }
      run += (u32)__popcll(mk);
    }
  }
  __syncthreads();

  // ---- phase 2: per-class greedy NMS in rank-prefix rounds, early exit >=300 ----
  int resume = 0, nk = 0;           // per-wave (uniform within wave)
  const int rl[4] = {512, 1024, 2048, NCAND};
  for (int round = 0; round < 4; ++round) {
    int rlim = rl[round];
    if (wid < 8) {
      int cnt = (int)clsCnt[wid], basec = (int)clsBase[wid];
      // hiC = first class-pos with rank >= rlim (ord2rank increasing per class)
      int lo = resume, hi2 = cnt;
      while (lo < hi2) { int mid = (lo + hi2) >> 1; if ((int)ord2rank[basec + mid] < rlim) lo = mid + 1; else hi2 = mid; }
      int hiC = lo;
      for (int p0 = resume; p0 < hiC; p0 += 64) {
        int p = p0 + lane;
        bool in = p < hiC;
        float4 q = in ? u.clsbox[basec + p] : make_float4(0.f, 0.f, 0.f, 0.f);
        float areaq = area_rn(q);
        wbox[wid][lane] = q; warea[wid][lane] = areaq;   // same-wave LDS, no barrier
        // phase A: vs my class's kept list (4-wide batched)
        bool sup = false;
        if (in) {
          int k = 0;
          for (; k + 4 <= nk; k += 4) {
            int i0 = kidxc[basec + k + 0], i1 = kidxc[basec + k + 1];
            int i2 = kidxc[basec + k + 2], i3 = kidxc[basec + k + 3];
            float4 b0 = u.clsbox[basec + i0], b1 = u.clsbox[basec + i1];
            float4 b2 = u.clsbox[basec + i2], b3 = u.clsbox[basec + i3];
            sup = sup | iou_gt4(b0, area_rn(b0), q, areaq) | iou_gt4(b1, area_rn(b1), q, areaq)
                      | iou_gt4(b2, area_rn(b2), q, areaq) | iou_gt4(b3, area_rn(b3), q, areaq);
          }
          for (; k < nk; ++k) {
            float4 bk = u.clsbox[basec + kidxc[basec + k]];
            sup = sup | iou_gt4(bk, area_rn(bk), q, areaq);
          }
        }
        u64 pending = __ballot((int)(in && !sup));
        // phase B: intra-group rows (j > lane), whole group is same class
        u64 row = 0;
        if ((pending >> lane) & 1ull) {
          u64 mine = pending & ~((2ull << lane) - 1ull);
          while (mine) {
            int j = __builtin_ctzll(mine); mine &= mine - 1ull;
            if (iou_gt4(q, areaq, wbox[wid][j], warea[wid][j])) row |= (1ull << j);
          }
        }
        u64 nz = __ballot((int)(row != 0ull));
        // phase C: parallel append when no intra-group suppression (common case)
        if ((nz & pending) == 0ull) {
          bool isp = ((pending >> lane) & 1ull) != 0;
          if (isp) {
            int grank = (int)__popcll(pending & lowm);
            kidxc[basec + nk + grank] = (u16)p;
            keptByRank[ord2rank[basec + p]] = 1;
          }
          nk += (int)__popcll(pending);
        } else {
          u64 rem = pending;
          while (rem) {
            int r = __builtin_ctzll(rem); rem &= rem - 1ull;
            if (lane == r) {
              kidxc[basec + nk] = (u16)(p0 + r);
              keptByRank[ord2rank[basec + p0 + r]] = 1;
            }
            ++nk;
            if ((nz >> r) & 1ull) {
              u64 rrow = (u64)__shfl((long long)row, r);
              rem &= ~rrow;
            }
          }
        }
      }
      resume = hiC;
    }
    // ---- count kept among rank < rlim; uniform break at >= NDET ----
    if (tid == 0) s_total = 0;
    __syncthreads();                        // phase-2 writes + reset visible
    u32 loc = 0;
    for (int r = tid; r < rlim; r += 1024) loc += (u32)keptByRank[r];
    for (int d = 32; d > 0; d >>= 1) loc += __shfl_down(loc, d);
    if (lane == 0 && loc) atomicAdd(&s_total, loc);
    __syncthreads();
    u32 total = s_total;
    __syncthreads();                        // all read before next reset
    if (total >= (u32)NDET || rlim >= NCAND) break;
  }

  // ---- phase 3: prefix-scan kept marks; emit first 300 in global rank order ----
  int rbase = tid * 5;                      // 1024*5 = 5120 covers 5000
  u32 v = 0;
  for (int j = 0; j < 5; ++j) { int r = rbase + j; if (r < NCAND && keptByRank[r]) v++; }
  u32 x = v;
  for (int d = 1; d < 64; d <<= 1) { u32 y = __shfl_up(x, d); if (lane >= d) x += y; }
  if (lane == 63) wsum[wid] = x;
  __syncthreads();
  if (tid == 0) { u32 a = 0; for (int w = 0; w < 16; ++w) { wpre[w] = a; a += wsum[w]; } s_total = a; }
  __syncthreads();
  u32 pos = wpre[wid] + x - v;              // exclusive prefix of my 5-rank window
  for (int j = 0; j < 5; ++j) {
    int r = rbase + j;
    if (r < NCAND && keptByRank[r]) {
      if (pos < NDET) {
        int io = origIdxByRank[r];
        float4 bx = cand_box[b * NCAND + io];
        float sc = cand_s[b * NCAND + io];
        float lb = (float)clsByRank[r];
        int idx = b * NDET + (int)pos;
        out[(size_t)idx * 4 + 0] = bx.x;
        out[(size_t)idx * 4 + 1] = bx.y;
        out[(size_t)idx * 4 + 2] = bx.z;
        out[(size_t)idx * 4 + 3] = bx.w;
        out[NB * NDET * 4 + idx] = sc;
        out[NB * NDET * 5 + idx] = lb;
      }
      pos++;
    }
  }
  u32 total = s_total < (u32)NDET ? s_total : (u32)NDET;
  for (int k2 = tid; k2 < NDET; k2 += 1024) {
    if ((u32)k2 >= total) {
      int idx = b * NDET + k2;
      out[(size_t)idx * 4 + 0] = 0.f;
      out[(size_t)idx * 4 + 1] = 0.f;
      out[(size_t)idx * 4 + 2] = 0.f;
      out[(size_t)idx * 4 + 3] = 0.f;
      out[NB * NDET * 4 + idx] = 0.f;
      out[NB * NDET * 5 + idx] = -1.0f;
    }
  }
}

extern "C" void kernel_launch(void* const* d_in, const int* in_sizes, int n_in,
                              void* d_out, int out_size, void* d_ws, size_t ws_size,
                              hipStream_t stream) {
  const float* cls[NLEV]; const float* reg[NLEV]; const float* anc[NLEV];
  bool dict_order = (n_in >= 2) && (in_sizes[1] == 4 * NREGCH * 64 * 64);
  for (int l = 0; l < NLEV; ++l) {
    if (dict_order) {
      cls[l] = (const float*)d_in[3 * l + 0];
      reg[l] = (const float*)d_in[3 * l + 1];
      anc[l] = (const float*)d_in[3 * l + 2];
    } else {
      cls[l] = (const float*)d_in[l];
      reg[l] = (const float*)d_in[NLEV + l];
      anc[l] = (const float*)d_in[2 * NLEV + l];
    }
  }

  char* ws = (char*)d_ws;
  size_t off = 0;
  auto alloc = [&](size_t bytes) -> void* {
    void* p = ws + off;
    off = (off + bytes + 255) & ~(size_t)255;
    return p;
  };
  u32*    selcnt   = (u32*)   alloc(20 * 4);
  u64*    sel      = (u64*)   alloc(20ULL * CAP * 8);
  float*  cand_s   = (float*) alloc((size_t)NB * NCAND * 4);
  u32*    cand_t   = (u32*)   alloc((size_t)NB * NCAND * 4);
  float4* cand_box = (float4*)alloc((size_t)NB * NCAND * 16);
  (void)ws_size; (void)out_size;

  hipMemsetAsync(selcnt, 0, 20 * 4, stream);

  ClsPtrs cp;
  for (int l = 0; l < NLEV; ++l) cp.p[l] = cls[l];
  LevelPtrs lp;
  for (int l = 0; l < NLEV; ++l) { lp.reg[l] = reg[l]; lp.anc[l] = anc[l]; }

  k_filter<<<NB * NCHUNK_IMG, 256, 0, stream>>>(cp, selcnt, sel);
  k_rank<<<NB * NLEV, 1024, 0, stream>>>(cp, selcnt, sel, cand_s, cand_t);
  k_decode<<<dim3((NCAND + 255) / 256, NB), 256, 0, stream>>>(cand_s, cand_t, lp, cand_box);
  k_detect<<<NB, 1024, 0, stream>>>(cand_s, cand_t, cand_box, (float*)d_out);
}

// Round 13
// 129.937 us; speedup vs baseline: 4.2594x; 1.3470x over previous
//
#include <hip/hip_runtime.h>
#include <stdint.h>
#include <stddef.h>

typedef unsigned int u32;
typedef unsigned long long u64;
typedef unsigned short u16;
typedef unsigned char u8;

#define NB 4
#define NLEV 5
#define NCH 72      // A*C = 9*8
#define NREGCH 36   // A*4
#define TOPK 1000
#define NCAND 5000  // NLEV*TOPK
#define NDET 300
#define NBINS 16384       // fallback hist: sigmoid float bits >> 16
#define CAP 8192          // per-(b,level) filtered-candidate buffer
#define FASTCAP 2048      // fast-path key limit (2 keys/thread @ 1024 thr)
#define CHUNK 8192
#define NCHUNK_IMG 50     // 36+9+3+1+1
#define IMGSZ 512.0f
#define SCORE_TH 0.05f
#define NMS_TH 0.5f
#define BBOX_CLIP_F 4.135166556742356f

__constant__ int c_f[NLEV]    = {64, 32, 16, 8, 4};
__constant__ int c_Nloc[NLEV] = {4096, 1024, 256, 64, 16};
__constant__ int c_lg2[NLEV]  = {12, 10, 8, 6, 4};
// logit prefilter thresholds: ~1400 expected survivors at levels 0-3 (10-sigma
// margins vs both TOPK=1000 and FASTCAP=2048); level 4 unfiltered (1152 total).
__constant__ float c_tau[NLEV] = {2.594f, 2.075f, 1.433f, 0.513f, -1e30f};

// ---- XLA-CPU-style sigmoid: logistic(x) = 0.5 + 0.5*tanh(0.5*x), fast-tanh poly, no FMA ----
__device__ __forceinline__ float xla_tanh_f32(float x) {
  float ax = fabsf(x);
  float xc = fminf(fmaxf(x, -7.90531110763549805f), 7.90531110763549805f);
  float x2 = __fmul_rn(xc, xc);
  float p = -2.76076847742355e-16f;
  p = __fadd_rn(__fmul_rn(x2, p), 2.00018790482477e-13f);
  p = __fadd_rn(__fmul_rn(x2, p), -8.60467152213735e-11f);
  p = __fadd_rn(__fmul_rn(x2, p), 5.12229709037114e-08f);
  p = __fadd_rn(__fmul_rn(x2, p), 1.48572235717979e-05f);
  p = __fadd_rn(__fmul_rn(x2, p), 6.37261928875436e-04f);
  p = __fadd_rn(__fmul_rn(x2, p), 4.89352455891786e-03f);
  float num = __fmul_rn(xc, p);
  float q = 1.19825839466702e-06f;
  q = __fadd_rn(__fmul_rn(x2, q), 1.18534705686654e-04f);
  q = __fadd_rn(__fmul_rn(x2, q), 2.26843463243900e-03f);
  q = __fadd_rn(__fmul_rn(x2, q), 4.89352518554385e-03f);
  float r = __fdiv_rn(num, q);
  return (ax < 0.0004f) ? x : r;
}
__device__ __forceinline__ float sigmoid_ref(float x) {
  return __fadd_rn(0.5f, __fmul_rn(0.5f, xla_tanh_f32(__fmul_rn(0.5f, x))));
}

struct ClsPtrs { const float* p[NLEV]; };
struct LevelPtrs { const float* reg[NLEV]; const float* anc[NLEV]; };

__device__ __forceinline__ void chunk_map(int bid, int& b, int& level, int& chunk) {
  b = bid / NCHUNK_IMG;
  int cid = bid % NCHUNK_IMG;
  if      (cid < 36) { level = 0; chunk = cid; }
  else if (cid < 45) { level = 1; chunk = cid - 36; }
  else if (cid < 48) { level = 2; chunk = cid - 45; }
  else if (cid < 49) { level = 3; chunk = cid - 48; }
  else               { level = 4; chunk = cid - 49; }
}

// exact BoxCoder decode + clip (identical _rn sequence as all passing rounds)
__device__ __forceinline__ float4 decode_box(const LevelPtrs& lp, int b, int lv, u32 e) {
  u32 anc = e >> 3;              // loc*9 + a
  int a = (int)(anc % 9u);
  int loc = (int)(anc / 9u);
  int f = c_f[lv];
  int Nloc = f * f;
  const float* rp = lp.reg[lv];
  const float* ap = lp.anc[lv] + (size_t)anc * 4;
  float r0 = rp[((size_t)b * NREGCH + (a * 4 + 0)) * Nloc + loc];
  float r1 = rp[((size_t)b * NREGCH + (a * 4 + 1)) * Nloc + loc];
  float r2 = rp[((size_t)b * NREGCH + (a * 4 + 2)) * Nloc + loc];
  float r3 = rp[((size_t)b * NREGCH + (a * 4 + 3)) * Nloc + loc];
  float a0 = ap[0], a1 = ap[1], a2 = ap[2], a3 = ap[3];
  float aw = __fsub_rn(a2, a0);
  float ah = __fsub_rn(a3, a1);
  float acx = __fadd_rn(a0, __fmul_rn(0.5f, aw));
  float acy = __fadd_rn(a1, __fmul_rn(0.5f, ah));
  float dw = fminf(r2, BBOX_CLIP_F);
  float dh = fminf(r3, BBOX_CLIP_F);
  float pcx = __fadd_rn(__fmul_rn(r0, aw), acx);
  float pcy = __fadd_rn(__fmul_rn(r1, ah), acy);
  float pw = __fmul_rn(expf(dw), aw);
  float ph = __fmul_rn(expf(dh), ah);
  float hx = __fmul_rn(0.5f, pw);
  float hy = __fmul_rn(0.5f, ph);
  float4 v;
  v.x = fminf(fmaxf(__fsub_rn(pcx, hx), 0.0f), IMGSZ);
  v.y = fminf(fmaxf(__fsub_rn(pcy, hy), 0.0f), IMGSZ);
  v.z = fminf(fmaxf(__fadd_rn(pcx, hx), 0.0f), IMGSZ);
  v.w = fminf(fmaxf(__fadd_rn(pcy, hy), 0.0f), IMGSZ);
  return v;
}

// ---- K1: logit-prefilter; ONE global atomic per block (two-pass ballot scheme) ----
__global__ __launch_bounds__(256)
void k_filter(ClsPtrs cp, u32* __restrict__ selcnt, u64* __restrict__ sel) {
  int b, level, chunk;
  chunk_map(blockIdx.x, b, level, chunk);
  int Nloc = c_Nloc[level], lg2 = c_lg2[level];
  int Nsc = Nloc * NCH;
  int g = b * NLEV + level;
  const float* cls = cp.p[level] + (size_t)b * Nsc;
  float tau = c_tau[level];
  int base = chunk * CHUNK;
  int end = base + CHUNK; if (end > Nsc) end = Nsc;
  int wid = threadIdx.x >> 6, lane = threadIdx.x & 63;
  u64 lowm = (1ull << lane) - 1ull;
  __shared__ u32 wcnt[4];
  __shared__ u32 s_gbase;
  u32 mycnt = 0;
  for (int i = base + threadIdx.x; i < end; i += 256) {
    u64 mk = __ballot((int)(cls[i] > tau));
    mycnt += (u32)__popcll(mk);
  }
  if (lane == 0) wcnt[wid] = mycnt;
  __syncthreads();
  u32 wbase = 0, tot = 0;
  for (int w = 0; w < 4; ++w) { u32 c = wcnt[w]; if (w < wid) wbase += c; tot += c; }
  if (threadIdx.x == 0 && tot) s_gbase = atomicAdd(&selcnt[g], tot);
  __syncthreads();
  if (!tot) return;
  u32 gb = s_gbase;
  u32 run = 0;
  for (int i = base + threadIdx.x; i < end; i += 256) {
    float x = cls[i];
    bool selp = x > tau;                 // monotone sigmoid => logit-space superset filter
    u64 mk = __ballot((int)selp);
    if (selp) {
      u32 pos = gb + wbase + run + (u32)__popcll(mk & lowm);
      if (pos < CAP) {
        u32 bits = __float_as_uint(sigmoid_ref(x));
        int ch = i >> lg2;
        int loc = i & (Nloc - 1);
        u32 e = (u32)(loc * NCH + ch);   // flat score index ((y*f+x)*9+a)*8+c
        sel[(size_t)g * CAP + pos] = ((u64)bits << 32) | (u32)(~e);
      }
    }
    run += (u32)__popcll(mk);
  }
}

// ---- K2: exact top-1000 by rank + fused box decode; guarded fast path + fallback ----
__global__ __launch_bounds__(1024)
void k_rank(ClsPtrs cp, LevelPtrs lp, const u32* __restrict__ selcnt,
            const u64* __restrict__ sel,
            float* __restrict__ cand_s, u32* __restrict__ cand_t,
            float4* __restrict__ cand_box) {
  __shared__ union { u32 hist[NBINS]; u64 keys[CAP]; } sh;  // 64 KB
  __shared__ u32 part[1024];
  __shared__ u32 s_last;
  __shared__ u32 s_cnt;
  __shared__ int s_cut;
  int g = blockIdx.x;
  int b = g / NLEV, l = g % NLEV;
  int Nloc = c_Nloc[l], lg2 = c_lg2[l];
  int Nsc = Nloc * NCH;
  int tid = threadIdx.x;
  int lane = tid & 63;
  u64 lowm = (1ull << lane) - 1ull;
  int obase = b * NCAND + l * TOPK;
  u32 cnt = selcnt[g];
  bool fast = (cnt >= TOPK) && (cnt <= FASTCAP);
  if (fast) {
    u32 m = cnt;
    for (u32 i = tid; i < m; i += 1024) sh.keys[i] = sel[(size_t)g * CAP + i];
    if (tid == 0) s_last = 0;
    __syncthreads();
    u64 k0a = ((u32)tid < m)        ? sh.keys[tid]        : 0ULL;
    u64 k0b = ((u32)tid + 1024 < m) ? sh.keys[tid + 1024] : 0ULL;
    u32 ra = 0, rb = 0;
    #pragma unroll 8
    for (u32 j = 0; j < m; ++j) {
      u64 kj = sh.keys[j];
      ra += (kj > k0a) ? 1u : 0u;
      rb += (kj > k0b) ? 1u : 0u;
    }
    if ((u32)tid < m && ra < TOPK) {
      cand_s[obase + ra] = __uint_as_float((u32)(k0a >> 32));
      u32 e = ~((u32)k0a);
      cand_t[obase + ra] = ((u32)l << 19) | (e & 0x7FFFFu);
      cand_box[obase + ra] = decode_box(lp, b, l, e);
      if (ra == TOPK - 1) s_last = (u32)(k0a >> 32);
    }
    if ((u32)tid + 1024 < m && rb < TOPK) {
      cand_s[obase + rb] = __uint_as_float((u32)(k0b >> 32));
      u32 e = ~((u32)k0b);
      cand_t[obase + rb] = ((u32)l << 19) | (e & 0x7FFFFu);
      cand_box[obase + rb] = decode_box(lp, b, l, e);
      if (rb == TOPK - 1) s_last = (u32)(k0b >> 32);
    }
    __syncthreads();
    // guard: rank-999 must beat the filter boundary by >64 ulps
    u32 bits_tau = __float_as_uint(sigmoid_ref(c_tau[l]));
    if ((int)cnt != Nsc && !(s_last > bits_tau + 64u)) fast = false;  // block-uniform
  }
  if (fast) return;

  // ---- fallback (never taken for this input; exact for any input) ----
  const float* cls = cp.p[l] + (size_t)b * Nsc;
  for (int i = tid; i < NBINS; i += 1024) sh.hist[i] = 0;
  if (tid == 0) s_cnt = 0;
  __syncthreads();
  for (int i = tid; i < Nsc; i += 1024) {
    float s = sigmoid_ref(cls[i]);
    atomicAdd(&sh.hist[__float_as_uint(s) >> 16], 1u);
  }
  __syncthreads();
  { u32 a = 0; for (int j = 0; j < 16; ++j) a += sh.hist[tid * 16 + j]; part[tid] = a; }
  __syncthreads();
  if (tid == 0) {
    u32 cum = 0; int cut = 0;
    for (int ch = 1023; ch >= 0; --ch) {
      if (cum + part[ch] >= TOPK) {
        u32 cc = cum;
        for (int bin = ch * 16 + 15;; --bin) { cc += sh.hist[bin]; if (cc >= TOPK) { cut = bin; break; } }
        break;
      }
      cum += part[ch];
    }
    s_cut = cut;
  }
  __syncthreads();
  int cut = s_cut;
  __syncthreads();
  for (int i = tid; i < Nsc; i += 1024) {
    float s = sigmoid_ref(cls[i]);
    u32 bits = __float_as_uint(s);
    bool selp = (int)(bits >> 16) >= cut;
    u64 mk = __ballot((int)selp);
    if (selp) {
      int ldr = __builtin_ctzll(mk);
      u32 pos0 = 0;
      if (lane == ldr) pos0 = atomicAdd(&s_cnt, (u32)__popcll(mk));
      pos0 = (u32)__shfl((int)pos0, ldr);
      u32 pos = pos0 + (u32)__popcll(mk & lowm);
      if (pos < CAP) {
        int ch = i >> lg2;
        int loc = i & (Nloc - 1);
        u32 e = (u32)(loc * NCH + ch);
        sh.keys[pos] = ((u64)bits << 32) | (u32)(~e);
      }
    }
  }
  __syncthreads();
  u32 m2 = s_cnt; if (m2 > CAP) m2 = CAP;
  for (u32 i = tid; i < m2; i += 1024) {
    u64 k0 = sh.keys[i];
    u32 r = 0;
    #pragma unroll 8
    for (u32 j = 0; j < m2; ++j) r += (sh.keys[j] > k0) ? 1u : 0u;
    if (r < TOPK) {
      cand_s[obase + r] = __uint_as_float((u32)(k0 >> 32));
      u32 e = ~((u32)k0);
      cand_t[obase + r] = ((u32)l << 19) | (e & 0x7FFFFu);
      cand_box[obase + r] = decode_box(lp, b, l, e);
    }
  }
  for (u32 r = m2 + tid; r < TOPK; r += 1024) {
    cand_s[obase + r] = -1.0f;
    cand_t[obase + r] = ((u32)l << 19) | r;
    cand_box[obase + r] = make_float4(0.f, 0.f, 0.f, 0.f);
  }
}

// ---- K3: global rank per candidate (wide: 5 blocks/image); scatter rank-ordered
//      offset-box + meta arrays. Valid ranks exact (monotone predicate even over
//      unsorted invalid tails); invalid ranks distinct-by-construction from back. ----
__global__ __launch_bounds__(1024)
void k_grank(const float* __restrict__ cand_s, const u32* __restrict__ cand_t,
             const float4* __restrict__ cand_box, u32* __restrict__ invCnt,
             float4* __restrict__ rboxOff, u32* __restrict__ rmeta) {
  __shared__ u64 keys[NCAND];   // 40 KB
  int b = blockIdx.y;
  int seg = blockIdx.x;         // level list 0..4
  int tid = threadIdx.x;
  for (int i = tid; i < NCAND; i += 1024) {
    float s = cand_s[b * NCAND + i];
    u32 t = cand_t[b * NCAND + i];
    u32 hi = (s > SCORE_TH) ? __float_as_uint(s) : 0u;
    keys[i] = ((u64)hi << 32) | (u32)(~t);
  }
  __syncthreads();
  if (tid >= TOPK) return;
  int i = seg * TOPK + tid;
  u64 k0 = keys[i];
  u32 hi = (u32)(k0 >> 32);
  u32 t = ~((u32)k0);
  int rank;
  u32 cls = 0;
  if (hi) {
    rank = tid;                               // own list: earlier entries greater
    for (int L = 0; L < NLEV; ++L) {
      if (L == seg) continue;
      const u64* A = keys + L * TOPK;
      int lo = 0, h2 = TOPK;                  // count of A[j] > k0 (monotone)
      while (lo < h2) { int mid = (lo + h2) >> 1; if (A[mid] > k0) lo = mid + 1; else h2 = mid; }
      rank += lo;
    }
    cls = t & 7u;
  } else {
    rank = (NCAND - 1) - (int)atomicAdd(&invCnt[b], 1u);  // distinct, all >= #valid
  }
  float4 v = cand_box[b * NCAND + i];
  float off = __fmul_rn((float)cls, IMGSZ + 1.0f);
  float4 q;
  q.x = __fadd_rn(v.x, off); q.y = __fadd_rn(v.y, off);
  q.z = __fadd_rn(v.z, off); q.w = __fadd_rn(v.w, off);
  rboxOff[b * NCAND + rank] = q;
  rmeta[b * NCAND + rank] = hi ? (((u32)i << 8) | cls) : 0xFFFFFFFFu;
}

// IoU > thresh predicate — identical _rn sequence as reference; div only when inter>0
__device__ __forceinline__ bool iou_gt4(float4 p, float pa, float4 q, float qa) {
  float ltx = fmaxf(p.x, q.x), lty = fmaxf(p.y, q.y);
  float rx  = fminf(p.z, q.z), ry  = fminf(p.w, q.w);
  float ww = fmaxf(__fsub_rn(rx, ltx), 0.0f);
  float hh = fmaxf(__fsub_rn(ry, lty), 0.0f);
  float inter = __fmul_rn(ww, hh);
  bool res = false;
  if (inter > 0.0f) {
    float denom = fmaxf(__fsub_rn(__fadd_rn(pa, qa), inter), 1e-7f);
    res = __fdiv_rn(inter, denom) > NMS_TH;
  }
  return res;
}
__device__ __forceinline__ float area_rn(float4 p) {
  return __fmul_rn(__fsub_rn(p.z, p.x), __fsub_rn(p.w, p.y));
}

// ---- K4: chunked-stage greedy NMS (round-10 structure) + emit ----
__global__ __launch_bounds__(1024)
void k_detect(const float* __restrict__ cand_s, const float4* __restrict__ cand_box,
              const float4* __restrict__ rboxOff, const u32* __restrict__ rmeta,
              float* __restrict__ out) {
  __shared__ float4 sb[1024];       // staged offset boxes (rank-ordered chunk)
  __shared__ u32    sm[1024];       // staged meta
  __shared__ float4 kbc[8][NDET];   // per-class kept boxes (offset space)
  __shared__ float  karc[8][NDET];
  __shared__ u32    kmeta[NDET];    // kept meta in global-rank order
  __shared__ float4 cbox[64];
  __shared__ float  carea[64];
  __shared__ u64    rowsh[64];
  __shared__ u64    supsh[8];
  __shared__ u32    kcnt[8];
  __shared__ u32    s_done, s_n;
  int b = blockIdx.x, tid = threadIdx.x;
  int wid = tid >> 6, lane = tid & 63;
  u64 lowm = (1ull << lane) - 1ull;
  if (tid < 8) kcnt[tid] = 0;
  if (tid == 0) { s_done = 0; s_n = 0; }
  int n = 0;                        // wave-0 authoritative
  bool fin = false;
  for (int c0 = 0; c0 < NCAND && !fin; c0 += 1024) {
    // stage chunk
    {
      int r = c0 + tid;
      bool ok = r < NCAND;
      sb[tid] = ok ? rboxOff[b * NCAND + r] : make_float4(0.f, 0.f, 0.f, 0.f);
      sm[tid] = ok ? rmeta[b * NCAND + r] : 0xFFFFFFFFu;
    }
    __syncthreads();
    for (int g0 = 0; g0 < 1024; g0 += 64) {
      int li = g0 + lane;
      u32 meta = sm[li];
      bool valid = meta != 0xFFFFFFFFu;
      int myc = valid ? (int)(meta & 0xFFu) : 0;
      float4 q = sb[li];
      float areaq = area_rn(q);
      if (wid == 0) { cbox[lane] = q; carea[lane] = areaq; }
      // phase A: waves 0-7 each test stride-8 slice of my class's kept list
      bool sup = false;
      if (wid < 8 && valid) {
        int cnt = (int)kcnt[myc];
        const float4* kb = kbc[myc];
        const float*  ka = karc[myc];
        for (int k = wid; k < cnt; k += 8)
          sup = sup | iou_gt4(kb[k], ka[k], q, areaq);
      }
      u64 bal = __ballot((int)sup);
      if (wid < 8 && lane == 0) supsh[wid] = bal;
      __syncthreads();
      if (wid == 0) {
        u64 supm = supsh[0] | supsh[1] | supsh[2] | supsh[3]
                 | supsh[4] | supsh[5] | supsh[6] | supsh[7];
        u64 validm = __ballot((int)valid);
        u64 pending = validm & ~supm;
        u64 cm_my = 0;
        for (int c = 0; c < 8; ++c) {
          u64 bc = __ballot((int)(valid && myc == c));
          if (myc == c) cm_my = bc;
        }
        // phase B: intra-group rows over same-class pending j > lane
        u64 row = 0;
        if ((pending >> lane) & 1ull) {
          u64 mine = pending & cm_my & ~((2ull << lane) - 1ull);
          while (mine) {
            int j = __builtin_ctzll(mine); mine &= mine - 1ull;
            if (iou_gt4(q, areaq, cbox[j], carea[j])) row |= (1ull << j);
          }
        }
        rowsh[lane] = row;
        u64 nz = __ballot((int)(row != 0ull));
        bool done = false;
        // phase C
        if ((nz & pending) == 0ull) {        // no intra-group suppression: parallel append
          int avail = NDET - n;
          bool isp = ((pending >> lane) & 1ull) != 0;
          int grank = (int)__popcll(pending & lowm);
          u64 keptb = __ballot((int)(isp && grank < avail));
          if (isp && grank < avail) {
            kmeta[n + grank] = meta;
            int crank = (int)__popcll(keptb & cm_my & lowm);
            int cb = (int)kcnt[myc];
            kbc[myc][cb + crank] = q; karc[myc][cb + crank] = areaq;
            if (crank == 0) kcnt[myc] = (u32)(cb + (int)__popcll(keptb & cm_my));
          }
          n += (int)__popcll(keptb);
          if (n >= NDET) done = true;
        } else {                             // rare: serial greedy resolution
          u64 rem = pending;
          while (rem) {
            int r = __builtin_ctzll(rem); rem &= rem - 1ull;
            if (lane == r) {
              kmeta[n] = meta;
              int cb = (int)kcnt[myc];
              kbc[myc][cb] = q; karc[myc][cb] = areaq; kcnt[myc] = (u32)(cb + 1);
            }
            ++n;
            if (n == NDET) { done = true; break; }
            if ((nz >> r) & 1ull) rem &= ~rowsh[r];
          }
        }
        if (__any((int)(!valid))) done = true;  // rank-ordered: rest invalid
        if (lane == 0) { s_done = done ? 1u : 0u; s_n = (u32)n; }
      }
      __syncthreads();
      if (s_done) { fin = true; break; }
    }
  }
  // ---- emit: boxes [B,300,4] ++ scores [B,300] ++ labels [B,300] ----
  int nf = (int)s_n;
  for (int k = tid; k < NDET; k += 1024) {
    float bx0 = 0.f, bx1 = 0.f, bx2 = 0.f, bx3 = 0.f, sc = 0.f, lb = -1.0f;
    if (k < nf) {
      u32 m = kmeta[k];
      int io = (int)(m >> 8);
      float4 v = cand_box[b * NCAND + io];
      bx0 = v.x; bx1 = v.y; bx2 = v.z; bx3 = v.w;
      sc = cand_s[b * NCAND + io];
      lb = (float)(m & 0xFFu);
    }
    int idx = b * NDET + k;
    out[(size_t)idx * 4 + 0] = bx0;
    out[(size_t)idx * 4 + 1] = bx1;
    out[(size_t)idx * 4 + 2] = bx2;
    out[(size_t)idx * 4 + 3] = bx3;
    out[NB * NDET * 4 + idx] = sc;
    out[NB * NDET * 5 + idx] = lb;
  }
}

extern "C" void kernel_launch(void* const* d_in, const int* in_sizes, int n_in,
                              void* d_out, int out_size, void* d_ws, size_t ws_size,
                              hipStream_t stream) {
  const float* cls[NLEV]; const float* reg[NLEV]; const float* anc[NLEV];
  bool dict_order = (n_in >= 2) && (in_sizes[1] == 4 * NREGCH * 64 * 64);
  for (int l = 0; l < NLEV; ++l) {
    if (dict_order) {
      cls[l] = (const float*)d_in[3 * l + 0];
      reg[l] = (const float*)d_in[3 * l + 1];
      anc[l] = (const float*)d_in[3 * l + 2];
    } else {
      cls[l] = (const float*)d_in[l];
      reg[l] = (const float*)d_in[NLEV + l];
      anc[l] = (const float*)d_in[2 * NLEV + l];
    }
  }

  char* ws = (char*)d_ws;
  size_t off = 0;
  auto alloc = [&](size_t bytes) -> void* {
    void* p = ws + off;
    off = (off + bytes + 255) & ~(size_t)255;
    return p;
  };
  u32*    ctrs     = (u32*)   alloc(24 * 4);   // [0,20): selcnt, [20,24): invCnt
  u64*    sel      = (u64*)   alloc(20ULL * CAP * 8);
  float*  cand_s   = (float*) alloc((size_t)NB * NCAND * 4);
  u32*    cand_t   = (u32*)   alloc((size_t)NB * NCAND * 4);
  float4* cand_box = (float4*)alloc((size_t)NB * NCAND * 16);
  float4* rboxOff  = (float4*)alloc((size_t)NB * NCAND * 16);
  u32*    rmeta    = (u32*)   alloc((size_t)NB * NCAND * 4);
  (void)ws_size; (void)out_size;

  u32* selcnt = ctrs;
  u32* invCnt = ctrs + 20;
  hipMemsetAsync(ctrs, 0, 24 * 4, stream);

  ClsPtrs cp;
  for (int l = 0; l < NLEV; ++l) cp.p[l] = cls[l];
  LevelPtrs lp;
  for (int l = 0; l < NLEV; ++l) { lp.reg[l] = reg[l]; lp.anc[l] = anc[l]; }

  k_filter<<<NB * NCHUNK_IMG, 256, 0, stream>>>(cp, selcnt, sel);
  k_rank<<<NB * NLEV, 1024, 0, stream>>>(cp, lp, selcnt, sel, cand_s, cand_t, cand_box);
  k_grank<<<dim3(NLEV, NB), 1024, 0, stream>>>(cand_s, cand_t, cand_box, invCnt, rboxOff, rmeta);
  k_detect<<<NB, 1024, 0, stream>>>(cand_s, cand_box, rboxOff, rmeta, (float*)d_out);
}

// Round 14
// 81.390 us; speedup vs baseline: 6.7999x; 1.5965x over previous
//
#include <hip/hip_runtime.h>
#include <stdint.h>
#include <stddef.h>

typedef unsigned int u32;
typedef unsigned long long u64;
typedef unsigned short u16;
typedef unsigned char u8;

#define NB 4
#define NLEV 5
#define NCH 72      // A*C = 9*8
#define NREGCH 36   // A*4
#define TOPK 1000
#define NCAND 5000  // NLEV*TOPK
#define NDET 300
#define NBINS 16384       // fallback hist: sigmoid float bits >> 16
#define RNB 4096          // counting-rank buckets (fast path)
#define CAP 8192          // per-(b,level) filtered-candidate buffer
#define FASTCAP 2048      // fast-path key limit (2 keys/thread @ 1024 thr)
#define CHUNK 8192
#define NCHUNK_IMG 50     // 36+9+3+1+1
#define IMGSZ 512.0f
#define SCORE_TH 0.05f
#define NMS_TH 0.5f
#define BBOX_CLIP_F 4.135166556742356f

__constant__ int c_f[NLEV]    = {64, 32, 16, 8, 4};
__constant__ int c_Nloc[NLEV] = {4096, 1024, 256, 64, 16};
__constant__ int c_lg2[NLEV]  = {12, 10, 8, 6, 4};
// logit prefilter thresholds: ~1400 expected survivors at levels 0-3 (10-sigma
// margins vs both TOPK=1000 and FASTCAP=2048); level 4 unfiltered (1152 total).
__constant__ float c_tau[NLEV] = {2.594f, 2.075f, 1.433f, 0.513f, -1e30f};
// counting-rank bucket shifts: (0x3F800000 - bits(sigmoid(tau))) >> shift < RNB
__constant__ int c_rshift[NLEV] = {10, 10, 11, 12, 18};

// ---- XLA-CPU-style sigmoid: logistic(x) = 0.5 + 0.5*tanh(0.5*x), fast-tanh poly, no FMA ----
__device__ __forceinline__ float xla_tanh_f32(float x) {
  float ax = fabsf(x);
  float xc = fminf(fmaxf(x, -7.90531110763549805f), 7.90531110763549805f);
  float x2 = __fmul_rn(xc, xc);
  float p = -2.76076847742355e-16f;
  p = __fadd_rn(__fmul_rn(x2, p), 2.00018790482477e-13f);
  p = __fadd_rn(__fmul_rn(x2, p), -8.60467152213735e-11f);
  p = __fadd_rn(__fmul_rn(x2, p), 5.12229709037114e-08f);
  p = __fadd_rn(__fmul_rn(x2, p), 1.48572235717979e-05f);
  p = __fadd_rn(__fmul_rn(x2, p), 6.37261928875436e-04f);
  p = __fadd_rn(__fmul_rn(x2, p), 4.89352455891786e-03f);
  float num = __fmul_rn(xc, p);
  float q = 1.19825839466702e-06f;
  q = __fadd_rn(__fmul_rn(x2, q), 1.18534705686654e-04f);
  q = __fadd_rn(__fmul_rn(x2, q), 2.26843463243900e-03f);
  q = __fadd_rn(__fmul_rn(x2, q), 4.89352518554385e-03f);
  float r = __fdiv_rn(num, q);
  return (ax < 0.0004f) ? x : r;
}
__device__ __forceinline__ float sigmoid_ref(float x) {
  return __fadd_rn(0.5f, __fmul_rn(0.5f, xla_tanh_f32(__fmul_rn(0.5f, x))));
}

struct ClsPtrs { const float* p[NLEV]; };
struct LevelPtrs { const float* reg[NLEV]; const float* anc[NLEV]; };

__device__ __forceinline__ void chunk_map(int bid, int& b, int& level, int& chunk) {
  b = bid / NCHUNK_IMG;
  int cid = bid % NCHUNK_IMG;
  if      (cid < 36) { level = 0; chunk = cid; }
  else if (cid < 45) { level = 1; chunk = cid - 36; }
  else if (cid < 48) { level = 2; chunk = cid - 45; }
  else if (cid < 49) { level = 3; chunk = cid - 48; }
  else               { level = 4; chunk = cid - 49; }
}

// exact BoxCoder decode + clip (identical _rn sequence as all passing rounds)
__device__ __forceinline__ float4 decode_box(const LevelPtrs& lp, int b, int lv, u32 e) {
  u32 anc = e >> 3;              // loc*9 + a
  int a = (int)(anc % 9u);
  int loc = (int)(anc / 9u);
  int f = c_f[lv];
  int Nloc = f * f;
  const float* rp = lp.reg[lv];
  const float* ap = lp.anc[lv] + (size_t)anc * 4;
  float r0 = rp[((size_t)b * NREGCH + (a * 4 + 0)) * Nloc + loc];
  float r1 = rp[((size_t)b * NREGCH + (a * 4 + 1)) * Nloc + loc];
  float r2 = rp[((size_t)b * NREGCH + (a * 4 + 2)) * Nloc + loc];
  float r3 = rp[((size_t)b * NREGCH + (a * 4 + 3)) * Nloc + loc];
  float a0 = ap[0], a1 = ap[1], a2 = ap[2], a3 = ap[3];
  float aw = __fsub_rn(a2, a0);
  float ah = __fsub_rn(a3, a1);
  float acx = __fadd_rn(a0, __fmul_rn(0.5f, aw));
  float acy = __fadd_rn(a1, __fmul_rn(0.5f, ah));
  float dw = fminf(r2, BBOX_CLIP_F);
  float dh = fminf(r3, BBOX_CLIP_F);
  float pcx = __fadd_rn(__fmul_rn(r0, aw), acx);
  float pcy = __fadd_rn(__fmul_rn(r1, ah), acy);
  float pw = __fmul_rn(expf(dw), aw);
  float ph = __fmul_rn(expf(dh), ah);
  float hx = __fmul_rn(0.5f, pw);
  float hy = __fmul_rn(0.5f, ph);
  float4 v;
  v.x = fminf(fmaxf(__fsub_rn(pcx, hx), 0.0f), IMGSZ);
  v.y = fminf(fmaxf(__fsub_rn(pcy, hy), 0.0f), IMGSZ);
  v.z = fminf(fmaxf(__fadd_rn(pcx, hx), 0.0f), IMGSZ);
  v.w = fminf(fmaxf(__fadd_rn(pcy, hy), 0.0f), IMGSZ);
  return v;
}

// ---- K1: logit-prefilter; ONE global atomic per block (two-pass ballot scheme) ----
__global__ __launch_bounds__(256)
void k_filter(ClsPtrs cp, u32* __restrict__ selcnt, u64* __restrict__ sel) {
  int b, level, chunk;
  chunk_map(blockIdx.x, b, level, chunk);
  int Nloc = c_Nloc[level], lg2 = c_lg2[level];
  int Nsc = Nloc * NCH;
  int g = b * NLEV + level;
  const float* cls = cp.p[level] + (size_t)b * Nsc;
  float tau = c_tau[level];
  int base = chunk * CHUNK;
  int end = base + CHUNK; if (end > Nsc) end = Nsc;
  int wid = threadIdx.x >> 6, lane = threadIdx.x & 63;
  u64 lowm = (1ull << lane) - 1ull;
  __shared__ u32 wcnt[4];
  __shared__ u32 s_gbase;
  u32 mycnt = 0;
  for (int i = base + threadIdx.x; i < end; i += 256) {
    u64 mk = __ballot((int)(cls[i] > tau));
    mycnt += (u32)__popcll(mk);
  }
  if (lane == 0) wcnt[wid] = mycnt;
  __syncthreads();
  u32 wbase = 0, tot = 0;
  for (int w = 0; w < 4; ++w) { u32 c = wcnt[w]; if (w < wid) wbase += c; tot += c; }
  if (threadIdx.x == 0 && tot) s_gbase = atomicAdd(&selcnt[g], tot);
  __syncthreads();
  if (!tot) return;
  u32 gb = s_gbase;
  u32 run = 0;
  for (int i = base + threadIdx.x; i < end; i += 256) {
    float x = cls[i];
    bool selp = x > tau;                 // monotone sigmoid => logit-space superset filter
    u64 mk = __ballot((int)selp);
    if (selp) {
      u32 pos = gb + wbase + run + (u32)__popcll(mk & lowm);
      if (pos < CAP) {
        u32 bits = __float_as_uint(sigmoid_ref(x));
        int ch = i >> lg2;
        int loc = i & (Nloc - 1);
        u32 e = (u32)(loc * NCH + ch);   // flat score index ((y*f+x)*9+a)*8+c
        sel[(size_t)g * CAP + pos] = ((u64)bits << 32) | (u32)(~e);
      }
    }
    run += (u32)__popcll(mk);
  }
}

// ---- K2: exact top-1000 via LDS counting-rank + fused decode; guarded fast path ----
__global__ __launch_bounds__(1024)
void k_rank(ClsPtrs cp, LevelPtrs lp, const u32* __restrict__ selcnt,
            const u64* __restrict__ sel,
            float* __restrict__ cand_s, u32* __restrict__ cand_t,
            float4* __restrict__ cand_box) {
  __shared__ union {
    struct { u64 keys2[FASTCAP]; u32 hist[RNB]; u32 pfx[RNB]; } f;  // 48 KB
    u32 histfb[NBINS];                                              // 64 KB
    u64 keysfb[CAP];                                                // 64 KB
  } sh;
  __shared__ u32 part[1024];
  __shared__ u32 s_last;
  __shared__ u32 s_cnt;
  __shared__ int s_cut;
  int g = blockIdx.x;
  int b = g / NLEV, l = g % NLEV;
  int Nloc = c_Nloc[l], lg2 = c_lg2[l];
  int Nsc = Nloc * NCH;
  int tid = threadIdx.x;
  int lane = tid & 63;
  u64 lowm = (1ull << lane) - 1ull;
  int obase = b * NCAND + l * TOPK;
  u32 cnt = selcnt[g];
  bool fast = (cnt >= TOPK) && (cnt <= FASTCAP);
  if (fast) {
    u32 m = cnt;
    int shift = c_rshift[l];
    for (int i = tid; i < RNB; i += 1024) { sh.f.hist[i] = 0; }
    if (tid == 0) s_last = 0;
    // my up-to-2 keys straight from global
    u64 k0a = ((u32)tid < m)        ? sel[(size_t)g * CAP + tid]        : 0ULL;
    u64 k0b = ((u32)tid + 1024 < m) ? sel[(size_t)g * CAP + tid + 1024] : 0ULL;
    // bucket: monotone DECREASING in key; clamp handles tails exactly
    auto bkt_of = [&](u64 k) -> int {
      int d = (int)0x3F800000 - (int)(u32)(k >> 32);
      if (d < 0) d = 0;
      int bq = d >> shift;
      return bq > RNB - 1 ? RNB - 1 : bq;
    };
    int ba = bkt_of(k0a), bb = bkt_of(k0b);
    __syncthreads();
    if ((u32)tid < m)        atomicAdd(&sh.f.hist[ba], 1u);
    if ((u32)tid + 1024 < m) atomicAdd(&sh.f.hist[bb], 1u);
    __syncthreads();
    // exclusive prefix scan of hist[RNB] -> pfx
    {
      int t4 = tid * 4;
      u32 h0 = sh.f.hist[t4], h1 = sh.f.hist[t4 + 1], h2 = sh.f.hist[t4 + 2], h3 = sh.f.hist[t4 + 3];
      u32 s4 = h0 + h1 + h2 + h3;
      u32 x = s4;
      for (int d = 1; d < 64; d <<= 1) { u32 y = __shfl_up(x, d); if (lane >= d) x += y; }
      if (lane == 63) part[tid >> 6] = x;
      __syncthreads();
      if (tid == 0) { u32 a = 0; for (int w = 0; w < 16; ++w) { u32 c = part[w]; part[w] = a; a += c; } }
      __syncthreads();
      u32 base2 = part[tid >> 6] + (x - s4);
      sh.f.pfx[t4]     = base2;
      sh.f.pfx[t4 + 1] = base2 + h0;
      sh.f.pfx[t4 + 2] = base2 + h0 + h1;
      sh.f.pfx[t4 + 3] = base2 + h0 + h1 + h2;
    }
    __syncthreads();
    // scatter into bucket-sorted keys2 (pfx becomes running insert ptr)
    if ((u32)tid < m)        { u32 p = atomicAdd(&sh.f.pfx[ba], 1u); sh.f.keys2[p] = k0a; }
    if ((u32)tid + 1024 < m) { u32 p = atomicAdd(&sh.f.pfx[bb], 1u); sh.f.keys2[p] = k0b; }
    __syncthreads();
    // exact rank = bucket_start + within-bucket count of greater keys; emit
    auto emit = [&](u64 k0, int bkt) {
      u32 endq = sh.f.pfx[bkt];            // after scatter: start + size
      u32 startq = endq - sh.f.hist[bkt];
      u32 r = startq;
      for (u32 j = startq; j < endq; ++j) r += (sh.f.keys2[j] > k0) ? 1u : 0u;
      if (r < TOPK) {
        u32 hi = (u32)(k0 >> 32);
        cand_s[obase + r] = __uint_as_float(hi);
        u32 e = ~((u32)k0);
        cand_t[obase + r] = ((u32)l << 19) | (e & 0x7FFFFu);
        cand_box[obase + r] = decode_box(lp, b, l, e);
        if (r == TOPK - 1) s_last = hi;
      }
    };
    if ((u32)tid < m)        emit(k0a, ba);
    if ((u32)tid + 1024 < m) emit(k0b, bb);
    __syncthreads();
    // guard: rank-999 must beat the filter boundary by >64 ulps
    u32 bits_tau = __float_as_uint(sigmoid_ref(c_tau[l]));
    if ((int)cnt != Nsc && !(s_last > bits_tau + 64u)) fast = false;  // block-uniform
  }
  if (fast) return;

  // ---- fallback (never taken for this input; exact for any input) ----
  const float* cls = cp.p[l] + (size_t)b * Nsc;
  __syncthreads();
  for (int i = tid; i < NBINS; i += 1024) sh.histfb[i] = 0;
  if (tid == 0) s_cnt = 0;
  __syncthreads();
  for (int i = tid; i < Nsc; i += 1024) {
    float s = sigmoid_ref(cls[i]);
    atomicAdd(&sh.histfb[__float_as_uint(s) >> 16], 1u);
  }
  __syncthreads();
  { u32 a = 0; for (int j = 0; j < 16; ++j) a += sh.histfb[tid * 16 + j]; part[tid] = a; }
  __syncthreads();
  if (tid == 0) {
    u32 cum = 0; int cut = 0;
    for (int ch = 1023; ch >= 0; --ch) {
      if (cum + part[ch] >= TOPK) {
        u32 cc = cum;
        for (int bin = ch * 16 + 15;; --bin) { cc += sh.histfb[bin]; if (cc >= TOPK) { cut = bin; break; } }
        break;
      }
      cum += part[ch];
    }
    s_cut = cut;
  }
  __syncthreads();
  int cut = s_cut;
  __syncthreads();                 // hist reads done before keys overwrite
  for (int i = tid; i < Nsc; i += 1024) {
    float s = sigmoid_ref(cls[i]);
    u32 bits = __float_as_uint(s);
    bool selp = (int)(bits >> 16) >= cut;
    u64 mk = __ballot((int)selp);
    if (selp) {
      int ldr = __builtin_ctzll(mk);
      u32 pos0 = 0;
      if (lane == ldr) pos0 = atomicAdd(&s_cnt, (u32)__popcll(mk));
      pos0 = (u32)__shfl((int)pos0, ldr);
      u32 pos = pos0 + (u32)__popcll(mk & lowm);
      if (pos < CAP) {
        int ch = i >> lg2;
        int loc = i & (Nloc - 1);
        u32 e = (u32)(loc * NCH + ch);
        sh.keysfb[pos] = ((u64)bits << 32) | (u32)(~e);
      }
    }
  }
  __syncthreads();
  u32 m2 = s_cnt; if (m2 > CAP) m2 = CAP;
  for (u32 i = tid; i < m2; i += 1024) {
    u64 k0 = sh.keysfb[i];
    u32 r = 0;
    #pragma unroll 8
    for (u32 j = 0; j < m2; ++j) r += (sh.keysfb[j] > k0) ? 1u : 0u;
    if (r < TOPK) {
      cand_s[obase + r] = __uint_as_float((u32)(k0 >> 32));
      u32 e = ~((u32)k0);
      cand_t[obase + r] = ((u32)l << 19) | (e & 0x7FFFFu);
      cand_box[obase + r] = decode_box(lp, b, l, e);
    }
  }
  for (u32 r = m2 + tid; r < TOPK; r += 1024) {
    cand_s[obase + r] = -1.0f;
    cand_t[obase + r] = ((u32)l << 19) | r;
    cand_box[obase + r] = make_float4(0.f, 0.f, 0.f, 0.f);
  }
}

// ---- K3: global rank per candidate (wide: 5 blocks/image); scatter rank-ordered
//      offset-box + meta arrays. Valid ranks exact; invalids distinct from back. ----
__global__ __launch_bounds__(1024)
void k_grank(const float* __restrict__ cand_s, const u32* __restrict__ cand_t,
             const float4* __restrict__ cand_box, u32* __restrict__ invCnt,
             float4* __restrict__ rboxOff, u32* __restrict__ rmeta) {
  __shared__ u64 keys[NCAND];   // 40 KB
  int b = blockIdx.y;
  int seg = blockIdx.x;         // level list 0..4
  int tid = threadIdx.x;
  for (int i = tid; i < NCAND; i += 1024) {
    float s = cand_s[b * NCAND + i];
    u32 t = cand_t[b * NCAND + i];
    u32 hi = (s > SCORE_TH) ? __float_as_uint(s) : 0u;
    keys[i] = ((u64)hi << 32) | (u32)(~t);
  }
  __syncthreads();
  if (tid >= TOPK) return;
  int i = seg * TOPK + tid;
  u64 k0 = keys[i];
  u32 hi = (u32)(k0 >> 32);
  u32 t = ~((u32)k0);
  int rank;
  u32 cls = 0;
  if (hi) {
    rank = tid;                               // own list: earlier entries greater
    for (int L = 0; L < NLEV; ++L) {
      if (L == seg) continue;
      const u64* A = keys + L * TOPK;
      int lo = 0, h2 = TOPK;                  // count of A[j] > k0 (monotone)
      while (lo < h2) { int mid = (lo + h2) >> 1; if (A[mid] > k0) lo = mid + 1; else h2 = mid; }
      rank += lo;
    }
    cls = t & 7u;
  } else {
    rank = (NCAND - 1) - (int)atomicAdd(&invCnt[b], 1u);  // distinct, all >= #valid
  }
  float4 v = cand_box[b * NCAND + i];
  float off = __fmul_rn((float)cls, IMGSZ + 1.0f);
  float4 q;
  q.x = __fadd_rn(v.x, off); q.y = __fadd_rn(v.y, off);
  q.z = __fadd_rn(v.z, off); q.w = __fadd_rn(v.w, off);
  rboxOff[b * NCAND + rank] = q;
  rmeta[b * NCAND + rank] = hi ? (((u32)i << 8) | cls) : 0xFFFFFFFFu;
}

// IoU > thresh predicate — identical _rn sequence as reference; div only when inter>0
__device__ __forceinline__ bool iou_gt4(float4 p, float pa, float4 q, float qa) {
  float ltx = fmaxf(p.x, q.x), lty = fmaxf(p.y, q.y);
  float rx  = fminf(p.z, q.z), ry  = fminf(p.w, q.w);
  float ww = fmaxf(__fsub_rn(rx, ltx), 0.0f);
  float hh = fmaxf(__fsub_rn(ry, lty), 0.0f);
  float inter = __fmul_rn(ww, hh);
  bool res = false;
  if (inter > 0.0f) {
    float denom = fmaxf(__fsub_rn(__fadd_rn(pa, qa), inter), 1e-7f);
    res = __fdiv_rn(inter, denom) > NMS_TH;
  }
  return res;
}
__device__ __forceinline__ float area_rn(float4 p) {
  return __fmul_rn(__fsub_rn(p.z, p.x), __fsub_rn(p.w, p.y));
}

// ---- K4: chunked-stage greedy NMS (round-10 structure) + emit ----
__global__ __launch_bounds__(1024)
void k_detect(const float* __restrict__ cand_s, const float4* __restrict__ cand_box,
              const float4* __restrict__ rboxOff, const u32* __restrict__ rmeta,
              float* __restrict__ out) {
  __shared__ float4 sb[1024];       // staged offset boxes (rank-ordered chunk)
  __shared__ u32    sm[1024];       // staged meta
  __shared__ float4 kbc[8][NDET];   // per-class kept boxes (offset space)
  __shared__ float  karc[8][NDET];
  __shared__ u32    kmeta[NDET];    // kept meta in global-rank order
  __shared__ float4 cbox[64];
  __shared__ float  carea[64];
  __shared__ u64    rowsh[64];
  __shared__ u64    supsh[8];
  __shared__ u32    kcnt[8];
  __shared__ u32    s_done, s_n;
  int b = blockIdx.x, tid = threadIdx.x;
  int wid = tid >> 6, lane = tid & 63;
  u64 lowm = (1ull << lane) - 1ull;
  if (tid < 8) kcnt[tid] = 0;
  if (tid == 0) { s_done = 0; s_n = 0; }
  int n = 0;                        // wave-0 authoritative
  bool fin = false;
  for (int c0 = 0; c0 < NCAND && !fin; c0 += 1024) {
    // stage chunk
    {
      int r = c0 + tid;
      bool ok = r < NCAND;
      sb[tid] = ok ? rboxOff[b * NCAND + r] : make_float4(0.f, 0.f, 0.f, 0.f);
      sm[tid] = ok ? rmeta[b * NCAND + r] : 0xFFFFFFFFu;
    }
    __syncthreads();
    for (int g0 = 0; g0 < 1024; g0 += 64) {
      int li = g0 + lane;
      u32 meta = sm[li];
      bool valid = meta != 0xFFFFFFFFu;
      int myc = valid ? (int)(meta & 0xFFu) : 0;
      float4 q = sb[li];
      float areaq = area_rn(q);
      if (wid == 0) { cbox[lane] = q; carea[lane] = areaq; }
      // phase A: waves 0-7 each test stride-8 slice of my class's kept list
      bool sup = false;
      if (wid < 8 && valid) {
        int cnt = (int)kcnt[myc];
        const float4* kb = kbc[myc];
        const float*  ka = karc[myc];
        for (int k = wid; k < cnt; k += 8)
          sup = sup | iou_gt4(kb[k], ka[k], q, areaq);
      }
      u64 bal = __ballot((int)sup);
      if (wid < 8 && lane == 0) supsh[wid] = bal;
      __syncthreads();
      if (wid == 0) {
        u64 supm = supsh[0] | supsh[1] | supsh[2] | supsh[3]
                 | supsh[4] | supsh[5] | supsh[6] | supsh[7];
        u64 validm = __ballot((int)valid);
        u64 pending = validm & ~supm;
        u64 cm_my = 0;
        for (int c = 0; c < 8; ++c) {
          u64 bc = __ballot((int)(valid && myc == c));
          if (myc == c) cm_my = bc;
        }
        // phase B: intra-group rows over same-class pending j > lane
        u64 row = 0;
        if ((pending >> lane) & 1ull) {
          u64 mine = pending & cm_my & ~((2ull << lane) - 1ull);
          while (mine) {
            int j = __builtin_ctzll(mine); mine &= mine - 1ull;
            if (iou_gt4(q, areaq, cbox[j], carea[j])) row |= (1ull << j);
          }
        }
        rowsh[lane] = row;
        u64 nz = __ballot((int)(row != 0ull));
        bool done = false;
        // phase C
        if ((nz & pending) == 0ull) {        // no intra-group suppression: parallel append
          int avail = NDET - n;
          bool isp = ((pending >> lane) & 1ull) != 0;
          int grank = (int)__popcll(pending & lowm);
          u64 keptb = __ballot((int)(isp && grank < avail));
          if (isp && grank < avail) {
            kmeta[n + grank] = meta;
            int crank = (int)__popcll(keptb & cm_my & lowm);
            int cb = (int)kcnt[myc];
            kbc[myc][cb + crank] = q; karc[myc][cb + crank] = areaq;
            if (crank == 0) kcnt[myc] = (u32)(cb + (int)__popcll(keptb & cm_my));
          }
          n += (int)__popcll(keptb);
          if (n >= NDET) done = true;
        } else {                             // rare: serial greedy resolution
          u64 rem = pending;
          while (rem) {
            int r = __builtin_ctzll(rem); rem &= rem - 1ull;
            if (lane == r) {
              kmeta[n] = meta;
              int cb = (int)kcnt[myc];
              kbc[myc][cb] = q; karc[myc][cb] = areaq; kcnt[myc] = (u32)(cb + 1);
            }
            ++n;
            if (n == NDET) { done = true; break; }
            if ((nz >> r) & 1ull) rem &= ~rowsh[r];
          }
        }
        if (__any((int)(!valid))) done = true;  // rank-ordered: rest invalid
        if (lane == 0) { s_done = done ? 1u : 0u; s_n = (u32)n; }
      }
      __syncthreads();
      if (s_done) { fin = true; break; }
    }
  }
  // ---- emit: boxes [B,300,4] ++ scores [B,300] ++ labels [B,300] ----
  int nf = (int)s_n;
  for (int k = tid; k < NDET; k += 1024) {
    float bx0 = 0.f, bx1 = 0.f, bx2 = 0.f, bx3 = 0.f, sc = 0.f, lb = -1.0f;
    if (k < nf) {
      u32 m = kmeta[k];
      int io = (int)(m >> 8);
      float4 v = cand_box[b * NCAND + io];
      bx0 = v.x; bx1 = v.y; bx2 = v.z; bx3 = v.w;
      sc = cand_s[b * NCAND + io];
      lb = (float)(m & 0xFFu);
    }
    int idx = b * NDET + k;
    out[(size_t)idx * 4 + 0] = bx0;
    out[(size_t)idx * 4 + 1] = bx1;
    out[(size_t)idx * 4 + 2] = bx2;
    out[(size_t)idx * 4 + 3] = bx3;
    out[NB * NDET * 4 + idx] = sc;
    out[NB * NDET * 5 + idx] = lb;
  }
}

extern "C" void kernel_launch(void* const* d_in, const int* in_sizes, int n_in,
                              void* d_out, int out_size, void* d_ws, size_t ws_size,
                              hipStream_t stream) {
  const float* cls[NLEV]; const float* reg[NLEV]; const float* anc[NLEV];
  bool dict_order = (n_in >= 2) && (in_sizes[1] == 4 * NREGCH * 64 * 64);
  for (int l = 0; l < NLEV; ++l) {
    if (dict_order) {
      cls[l] = (const float*)d_in[3 * l + 0];
      reg[l] = (const float*)d_in[3 * l + 1];
      anc[l] = (const float*)d_in[3 * l + 2];
    } else {
      cls[l] = (const float*)d_in[l];
      reg[l] = (const float*)d_in[NLEV + l];
      anc[l] = (const float*)d_in[2 * NLEV + l];
    }
  }

  char* ws = (char*)d_ws;
  size_t off = 0;
  auto alloc = [&](size_t bytes) -> void* {
    void* p = ws + off;
    off = (off + bytes + 255) & ~(size_t)255;
    return p;
  };
  u32*    ctrs     = (u32*)   alloc(24 * 4);   // [0,20): selcnt, [20,24): invCnt
  u64*    sel      = (u64*)   alloc(20ULL * CAP * 8);
  float*  cand_s   = (float*) alloc((size_t)NB * NCAND * 4);
  u32*    cand_t   = (u32*)   alloc((size_t)NB * NCAND * 4);
  float4* cand_box = (float4*)alloc((size_t)NB * NCAND * 16);
  float4* rboxOff  = (float4*)alloc((size_t)NB * NCAND * 16);
  u32*    rmeta    = (u32*)   alloc((size_t)NB * NCAND * 4);
  (void)ws_size; (void)out_size;

  u32* selcnt = ctrs;
  u32* invCnt = ctrs + 20;
  hipMemsetAsync(ctrs, 0, 24 * 4, stream);

  ClsPtrs cp;
  for (int l = 0; l < NLEV; ++l) cp.p[l] = cls[l];
  LevelPtrs lp;
  for (int l = 0; l < NLEV; ++l) { lp.reg[l] = reg[l]; lp.anc[l] = anc[l]; }

  k_filter<<<NB * NCHUNK_IMG, 256, 0, stream>>>(cp, selcnt, sel);
  k_rank<<<NB * NLEV, 1024, 0, stream>>>(cp, lp, selcnt, sel, cand_s, cand_t, cand_box);
  k_grank<<<dim3(NLEV, NB), 1024, 0, stream>>>(cand_s, cand_t, cand_box, invCnt, rboxOff, rmeta);
  k_detect<<<NB, 1024, 0, stream>>>(cand_s, cand_box, rboxOff, rmeta, (float*)d_out);
}